// Round 11
// baseline (1753.969 us; speedup 1.0000x reference)
//
#include <hip/hip_runtime.h>
#include <hip/hip_bf16.h>

// GraphRNNSeq2SeqDecoder — MI355X implementation.
// R11: GRU slot restructured — wave-local shfl reduction (no red[] LDS, no
// compute->gate syncs), f16 exchange buffer h16 (halved panel traffic),
// hoisted biases, single-wave flag poll. Shadow reverted to R9 scope
// (proj GEMMs + out_w transpose only).

#define B_   16
#define T_   32
#define S_   512
#define R_   8
#define L_   256
#define RL_  2048
#define H_   512
#define V_   50000
#define NL_  3
#define OOV_ 50
#define M_   512
#define FINW 50050
#define S2C  2.8853900817779268f   // 2*log2(e)
#define GRUB 128
#define NCONV 128
#define HP16 520

typedef __attribute__((ext_vector_type(8))) short    short8;
typedef __attribute__((ext_vector_type(4))) float    f32x4;
typedef __attribute__((ext_vector_type(2))) _Float16 h2;
typedef __attribute__((ext_vector_type(8))) _Float16 h8;
typedef unsigned short u16;
typedef unsigned int   u32;
typedef unsigned long long u64;

#if __has_builtin(__builtin_amdgcn_exp2f)
#define EXP2F __builtin_amdgcn_exp2f
#else
#define EXP2F exp2f
#endif
#if __has_builtin(__builtin_amdgcn_rcpf)
#define RCPF __builtin_amdgcn_rcpf
#else
#define RCPF(x) (1.f/(x))
#endif

__device__ __forceinline__ float bf2f(u16 u){
  union { u32 i; float f; } v; v.i = ((u32)u) << 16; return v.f;
}
__device__ __forceinline__ u16 f2bf(float f){
  union { float f; u32 i; } v; v.f = f;
  return (u16)((v.i + 0x7FFFu + ((v.i >> 16) & 1u)) >> 16);   // RNE
}
__device__ __forceinline__ u16 f2h(float f){
  union { _Float16 h; u16 u; } v; v.h = (_Float16)f; return v.u;
}
__device__ __forceinline__ float tanh_(float x){
  float e = __expf(2.f * x);
  return 1.f - 2.f / (e + 1.f);
}
__device__ __forceinline__ float sigmoid_(float x){
  return 1.f / (1.f + __expf(-x));
}
__device__ __forceinline__ float dot8h(h8 w, h8 x, float acc){
#if __has_builtin(__builtin_amdgcn_fdot2)
  acc = __builtin_amdgcn_fdot2((h2){w[0], w[1]}, (h2){x[0], x[1]}, acc, false);
  acc = __builtin_amdgcn_fdot2((h2){w[2], w[3]}, (h2){x[2], x[3]}, acc, false);
  acc = __builtin_amdgcn_fdot2((h2){w[4], w[5]}, (h2){x[4], x[5]}, acc, false);
  acc = __builtin_amdgcn_fdot2((h2){w[6], w[7]}, (h2){x[6], x[7]}, acc, false);
#else
  #pragma unroll
  for (int q = 0; q < 8; q++) acc += (float)w[q] * (float)x[q];
#endif
  return acc;
}
__device__ __forceinline__ u64 allc(const u64* p){
  return __hip_atomic_load(p, __ATOMIC_RELAXED, __HIP_MEMORY_SCOPE_AGENT);
}
__device__ __forceinline__ float allcf(const float* p){
  u32 v = __hip_atomic_load((const u32*)p, __ATOMIC_RELAXED, __HIP_MEMORY_SCOPE_AGENT);
  union { u32 i; float f; } c; c.i = v; return c.f;
}

// ---------------- conversions ----------------

__global__ __launch_bounds__(256) void k_embed(const int* __restrict__ tokens,
                                               const float* __restrict__ embed_w,
                                               u16* __restrict__ x_bf){
  int rid = blockIdx.x;
  long tok = (long)tokens[rid];
  const float* src = embed_w + tok * H_;
  u16* dst = x_bf + (long)rid * H_;
  for (int e = threadIdx.x; e < H_; e += 256) dst[e] = f2bf(src[e]);
}

struct CJ { const float* s; u16* d; long n; int f16; };

__global__ __launch_bounds__(256) void k_conv6(CJ j0, CJ j1, CJ j2, CJ j3, CJ j4, CJ j5){
  int y = blockIdx.y;
  CJ j = (y == 0) ? j0 : (y == 1) ? j1 : (y == 2) ? j2 : (y == 3) ? j3 : (y == 4) ? j4 : j5;
  long n4 = j.n >> 2;
  long i = (long)blockIdx.x * 256 + threadIdx.x;
  long stride = (long)gridDim.x * 256;
  if (j.f16){
    for (; i < n4; i += stride){
      f32x4 v = *(const f32x4*)(j.s + 4 * i);
      u64 p = (u64)f2h(v[0]) | ((u64)f2h(v[1]) << 16)
            | ((u64)f2h(v[2]) << 32) | ((u64)f2h(v[3]) << 48);
      *(u64*)(j.d + 4 * i) = p;
    }
  } else {
    for (; i < n4; i += stride){
      f32x4 v = *(const f32x4*)(j.s + 4 * i);
      u64 p = (u64)f2bf(v[0]) | ((u64)f2bf(v[1]) << 16)
            | ((u64)f2bf(v[2]) << 32) | ((u64)f2bf(v[3]) << 48);
      *(u64*)(j.d + 4 * i) = p;
    }
  }
}

// dst[c][r] = bf16(src[r][c])
__global__ __launch_bounds__(256) void k_convT(const float* __restrict__ src, int Rr, int Cc,
                                               u16* __restrict__ dst){
  __shared__ float tile[32][33];
  int c0 = blockIdx.x * 32, r0 = blockIdx.y * 32;
  int tx = threadIdx.x & 31, ty = threadIdx.x >> 5;
  for (int i = ty; i < 32; i += 8){
    int r = r0 + i, c = c0 + tx;
    tile[i][tx] = (r < Rr && c < Cc) ? src[(long)r * Cc + c] : 0.f;
  }
  __syncthreads();
  for (int i = ty; i < 32; i += 8){
    int c = c0 + i, r = r0 + tx;
    if (c < Cc && r < Rr) dst[(long)c * Rr + r] = f2bf(tile[tx][i]);
  }
}

__global__ __launch_bounds__(256) void k_convT6(const float* s0, const float* s1,
    const float* s2, const float* s3, const float* s4, const float* s5,
    u16* __restrict__ dstb){
  int z = blockIdx.z;
  const float* src = (z == 0) ? s0 : (z == 1) ? s1 : (z == 2) ? s2
                   : (z == 3) ? s3 : (z == 4) ? s4 : s5;
  u16* dst = dstb + (long)z * H_ * H_;
  __shared__ float tile[32][33];
  int c0 = blockIdx.x * 32, r0 = blockIdx.y * 32;
  int tx = threadIdx.x & 31, ty = threadIdx.x >> 5;
  for (int i = ty; i < 32; i += 8)
    tile[i][tx] = src[(long)(r0 + i) * H_ + c0 + tx];
  __syncthreads();
  for (int i = ty; i < 32; i += 8)
    dst[(long)(c0 + i) * H_ + r0 + tx] = f2bf(tile[tx][i]);
}

// ---------------- bf16 MFMA GEMM tile (device fn; no syncthreads) ----------------

__device__ void dev_gemm_tile(const u16* __restrict__ A, int lda,
                              const u16* __restrict__ W, int ldw,
                              const float* __restrict__ bias,
                              void* __restrict__ Cv, long ldc,
                              int N, int K, int c_bf16, float cscale,
                              int bx, int by, int t256){
  int wave = t256 >> 6, lane = t256 & 63;
  int m0 = bx * 128 + (wave >> 1) * 64;
  int n0 = by * 128 + (wave & 1) * 64;
  int lr = lane & 15, lk = (lane >> 4) * 8;
  f32x4 acc[4][4];
  #pragma unroll
  for (int i = 0; i < 4; i++)
    #pragma unroll
    for (int j = 0; j < 4; j++) acc[i][j] = (f32x4){0.f, 0.f, 0.f, 0.f};

  short8 a0[4], b0[4];
  #pragma unroll
  for (int i = 0; i < 4; i++)
    a0[i] = *(const short8*)(A + (long)(m0 + i * 16 + lr) * lda + lk);
  #pragma unroll
  for (int j = 0; j < 4; j++){
    int c = n0 + j * 16 + lr;
    b0[j] = (c < N) ? *(const short8*)(W + (long)c * ldw + lk) : (short8){0,0,0,0,0,0,0,0};
  }
  for (int k0 = 0; k0 < K; k0 += 32){
    short8 a1[4], b1[4];
    if (k0 + 32 < K){
      int kn = k0 + 32 + lk;
      #pragma unroll
      for (int i = 0; i < 4; i++)
        a1[i] = *(const short8*)(A + (long)(m0 + i * 16 + lr) * lda + kn);
      #pragma unroll
      for (int j = 0; j < 4; j++){
        int c = n0 + j * 16 + lr;
        b1[j] = (c < N) ? *(const short8*)(W + (long)c * ldw + kn) : (short8){0,0,0,0,0,0,0,0};
      }
    }
    #pragma unroll
    for (int i = 0; i < 4; i++)
      #pragma unroll
      for (int j = 0; j < 4; j++)
        acc[i][j] = __builtin_amdgcn_mfma_f32_16x16x32_bf16(a0[i], b0[j], acc[i][j], 0, 0, 0);
    #pragma unroll
    for (int i = 0; i < 4; i++) a0[i] = a1[i];
    #pragma unroll
    for (int j = 0; j < 4; j++) b0[j] = b1[j];
  }
  int rr = (lane >> 4) * 4;                 // C/D: col = lane&15, row = (lane>>4)*4 + e
  #pragma unroll
  for (int j = 0; j < 4; j++){
    int c = n0 + j * 16 + lr;
    if (c >= N) continue;
    float bv = bias ? bias[c] : 0.f;
    #pragma unroll
    for (int i = 0; i < 4; i++){
      #pragma unroll
      for (int e = 0; e < 4; e++){
        long r = m0 + i * 16 + rr + e;
        float v = fmaf(acc[i][j][e], cscale, bv);
        if (c_bf16) ((u16*)Cv)[r * ldc + c] = f2bf(v);
        else        ((float*)Cv)[r * ldc + c] = v;
      }
    }
  }
}

__global__ __launch_bounds__(256) void k_gemm_nt(const u16* __restrict__ A, int lda,
                                                 const u16* __restrict__ W, int ldw,
                                                 const float* __restrict__ bias,
                                                 void* __restrict__ Cv, long ldc,
                                                 int N, int K, int c_bf16, float cscale){
  dev_gemm_tile(A, lda, W, ldw, bias, Cv, ldc, N, K, c_bf16, cscale,
                blockIdx.x, blockIdx.y, threadIdx.x);
}

// ---------------- out-GEMM: logits + LDS epilogue + pm/ps ----------------

__global__ __launch_bounds__(256) void k_gemm_out(const u16* __restrict__ A,
    const u16* __restrict__ W, const float* __restrict__ bias,
    float* __restrict__ fin, float* __restrict__ pm, float* __restrict__ ps){
  const int N = V_;
  __shared__ float cbuf[128][132];
  __shared__ float smx[128][2], ssx[128][2];
  int tid = threadIdx.x;
  int wave = tid >> 6, lane = tid & 63;
  int mb = blockIdx.x * 128, nb = blockIdx.y * 128;
  int m0 = mb + (wave >> 1) * 64;
  int n0 = nb + (wave & 1) * 64;
  int lr = lane & 15, lk = (lane >> 4) * 8;
  f32x4 acc[4][4];
  #pragma unroll
  for (int i = 0; i < 4; i++)
    #pragma unroll
    for (int j = 0; j < 4; j++) acc[i][j] = (f32x4){0.f, 0.f, 0.f, 0.f};

  short8 a0[4], b0[4];
  #pragma unroll
  for (int i = 0; i < 4; i++)
    a0[i] = *(const short8*)(A + (long)(m0 + i * 16 + lr) * 512 + lk);
  #pragma unroll
  for (int j = 0; j < 4; j++){
    int c = n0 + j * 16 + lr;
    b0[j] = (c < N) ? *(const short8*)(W + (long)c * 512 + lk) : (short8){0,0,0,0,0,0,0,0};
  }
  for (int k0 = 0; k0 < 512; k0 += 32){
    short8 a1[4], b1[4];
    if (k0 + 32 < 512){
      int kn = k0 + 32 + lk;
      #pragma unroll
      for (int i = 0; i < 4; i++)
        a1[i] = *(const short8*)(A + (long)(m0 + i * 16 + lr) * 512 + kn);
      #pragma unroll
      for (int j = 0; j < 4; j++){
        int c = n0 + j * 16 + lr;
        b1[j] = (c < N) ? *(const short8*)(W + (long)c * 512 + kn) : (short8){0,0,0,0,0,0,0,0};
      }
    }
    #pragma unroll
    for (int i = 0; i < 4; i++)
      #pragma unroll
      for (int j = 0; j < 4; j++)
        acc[i][j] = __builtin_amdgcn_mfma_f32_16x16x32_bf16(a0[i], b0[j], acc[i][j], 0, 0, 0);
    #pragma unroll
    for (int i = 0; i < 4; i++) a0[i] = a1[i];
    #pragma unroll
    for (int j = 0; j < 4; j++) b0[j] = b1[j];
  }
  int rr = (lane >> 4) * 4;
  int rloc0 = (wave >> 1) * 64, cloc0 = (wave & 1) * 64;
  #pragma unroll
  for (int j = 0; j < 4; j++){
    int c = n0 + j * 16 + lr;
    float bv = (c < N) ? bias[c] : 0.f;
    #pragma unroll
    for (int i = 0; i < 4; i++){
      #pragma unroll
      for (int e = 0; e < 4; e++)
        cbuf[rloc0 + i * 16 + rr + e][cloc0 + j * 16 + lr] = acc[i][j][e] + bv;
    }
  }
  __syncthreads();
  int rl = tid >> 1, ch = tid & 1;
  int cbase = ch * 64;
  int cg = nb + cbase;
  long gbase = (long)(mb + rl) * FINW + cg;
  float mp = -1e30f;
  #pragma unroll 8
  for (int k = 0; k < 64; k += 2){
    float x0 = cbuf[rl][cbase + k], x1 = cbuf[rl][cbase + k + 1];
    float2 xy; xy.x = x0; xy.y = x1;
    *(float2*)(fin + gbase + k) = xy;
    if (cg + k < N)     mp = fmaxf(mp, x0);
    if (cg + k + 1 < N) mp = fmaxf(mp, x1);
  }
  float sp = 0.f;
  #pragma unroll 8
  for (int k = 0; k < 64; k++){
    if (cg + k < N) sp += __expf(cbuf[rl][cbase + k] - mp);
  }
  smx[rl][ch] = mp; ssx[rl][ch] = sp;
  __syncthreads();
  if (tid < 128){
    float ma = smx[tid][0], mb2 = smx[tid][1];
    float M = fmaxf(ma, mb2);
    float S = ssx[tid][0] * __expf(ma - M) + ssx[tid][1] * __expf(mb2 - M);
    long row = mb + tid;
    pm[row * 392 + blockIdx.y] = M;
    ps[row * 392 + blockIdx.y] = S;
  }
}

// ---------------- mega kernel ----------------
// blocks [0,128): GRU recurrence — wave-local shfl reduction, f16 exchange.
//   thread: jj = tid>>7 (j = bx*4+jj), b = (tid>>3)&15, ks = tid&7.
//   8 ks lanes are adjacent in-wave -> shfl_xor(1,2,4) reduction, gate at ks==0.
// blocks [128,256): shadow — proj GEMM tiles, then out_w transpose.

__global__ __launch_bounds__(512) void k_gru_mega(
    const float* __restrict__ gx0, const u16* __restrict__ wih_h,
    const u16* __restrict__ whh_h, const float* __restrict__ bih,
    const float* __restrict__ bhh, const float* __restrict__ hidden0,
    float* __restrict__ h_all, u16* __restrict__ h16,
    u16* __restrict__ ch_bf, unsigned int* cnt,
    const float* __restrict__ out_w, u16* __restrict__ outwT,
    const u16* __restrict__ cwr_bf, const u16* __restrict__ rwr_bf,
    const u16* __restrict__ rdr_bf, const u16* __restrict__ WT,
    u16* __restrict__ enc_bf, u16* __restrict__ wp_bf,
    float* __restrict__ doc_proj, int do_shadow){
  __shared__ u16 P0[16][HP16], P1[16][HP16], P2[16][HP16];
  __shared__ float tconv[2][32][33];
  int bid = blockIdx.x;
  int tid = threadIdx.x;

  if (bid >= GRUB){
    if (!do_shadow) return;
    int wid = bid - GRUB;
    int half = tid >> 8, t256 = tid & 255;
    int worker = wid * 2 + half;
    // --- proj GEMM tiles (enc 256 | wp 1024 | doc 4) ---
    for (int tile = worker; tile < 1284; tile += 256){
      if (tile < 256)
        dev_gemm_tile(cwr_bf, H_, WT, H_, (const float*)0, (void*)enc_bf, H_,
                      H_, H_, 1, S2C, tile >> 2, tile & 3, t256);
      else if (tile < 1280){
        int t = tile - 256;
        dev_gemm_tile(rwr_bf, H_, WT + 2 * H_ * H_, H_, (const float*)0, (void*)wp_bf, H_,
                      H_, H_, 1, S2C, t >> 2, t & 3, t256);
      } else
        dev_gemm_tile(rdr_bf, H_, WT + H_ * H_, H_, (const float*)0, (void*)doc_proj, H_,
                      H_, H_, 0, S2C, 0, tile - 1280, t256);
    }
    __syncthreads();
    // --- transpose out_w [512][50000] f32 -> outwT [50000][512] bf16 ---
    int sub = half, tx = t256 & 31, ty = t256 >> 5;
    const int NT = 1563 * 16;
    for (int base = wid * 2; base < NT; base += NCONV * 2){
      int tile = base + sub;
      bool act = tile < NT;
      int cx = act ? (tile % 1563) : 0;
      int ry = act ? (tile / 1563) : 0;
      int c0 = cx * 32, r0 = ry * 32;
      if (act){
        for (int i = ty; i < 32; i += 8){
          int c = c0 + tx;
          tconv[sub][i][tx] = (c < V_) ? out_w[(long)(r0 + i) * V_ + c] : 0.f;
        }
      }
      __syncthreads();
      if (act){
        for (int i = ty; i < 32; i += 8){
          int c = c0 + i;
          if (c < V_) outwT[(long)c * H_ + r0 + tx] = f2bf(tconv[sub][tx][i]);
        }
      }
      __syncthreads();
    }
    return;
  }

  int bx = bid;
  int jj = tid >> 7, b = (tid >> 3) & 15, ks = tid & 7;
  int j = bx * 4 + jj;
  int kbase = ks * 64;
  int srow = tid >> 5, sl32 = tid & 31;

  // hoisted biases (ks==0 lanes only use them)
  float bh00 = 0, bh01 = 0, bh02 = 0, bh10 = 0, bh11 = 0, bh12 = 0,
        bh20 = 0, bh21 = 0, bh22 = 0, bi10 = 0, bi11 = 0, bi12 = 0,
        bi20 = 0, bi21 = 0, bi22 = 0;
  if (ks == 0){
    bh00 = bhh[0 * 1536 + 0 * H_ + j]; bh01 = bhh[0 * 1536 + 1 * H_ + j];
    bh02 = bhh[0 * 1536 + 2 * H_ + j];
    bh10 = bhh[1 * 1536 + 0 * H_ + j]; bh11 = bhh[1 * 1536 + 1 * H_ + j];
    bh12 = bhh[1 * 1536 + 2 * H_ + j];
    bh20 = bhh[2 * 1536 + 0 * H_ + j]; bh21 = bhh[2 * 1536 + 1 * H_ + j];
    bh22 = bhh[2 * 1536 + 2 * H_ + j];
    bi10 = bih[1 * 1536 + 0 * H_ + j]; bi11 = bih[1 * 1536 + 1 * H_ + j];
    bi12 = bih[1 * 1536 + 2 * H_ + j];
    bi20 = bih[2 * 1536 + 0 * H_ + j]; bi21 = bih[2 * 1536 + 1 * H_ + j];
    bi22 = bih[2 * 1536 + 2 * H_ + j];
  }

  for (int s = 0; s < T_ + NL_ - 1; s++){
    int t0 = s, t1 = s - 1, t2v = s - 2;
    bool a0 = (t0 < T_);
    bool a1 = (t1 >= 0 && t1 < T_);
    bool a2 = (t2v >= 0 && t2v < T_);
    // ---- gate-side prefetch (exact f32 carried state + gx0), ks==0 lanes ----
    float hp0 = 0.f, hp1 = 0.f, hp2 = 0.f, g0r = 0.f, g1r = 0.f, g2r = 0.f;
    if (ks == 0){
      if (a0){
        hp0 = (t0 == 0) ? hidden0[(0 * B_ + b) * H_ + j]
                        : allcf(h_all + (long)((0 * T_ + t0 - 1) * B_ + b) * H_ + j);
        const float* g = gx0 + (long)(b * T_ + t0) * 1536 + j;
        g0r = g[0]; g1r = g[512]; g2r = g[1024];
      }
      if (a1) hp1 = (t1 == 0) ? hidden0[(1 * B_ + b) * H_ + j]
                              : allcf(h_all + (long)((1 * T_ + t1 - 1) * B_ + b) * H_ + j);
      if (a2) hp2 = (t2v == 0) ? hidden0[(2 * B_ + b) * H_ + j]
                               : allcf(h_all + (long)((2 * T_ + t2v - 1) * B_ + b) * H_ + j);
    }
    // ---- stage 3 f16 panels: P0=h[0][s-1], P1=h[1][s-2], P2=h[2][s-3] ----
    if (a0 && t0 == 0){
      const f32x4* p = (const f32x4*)(hidden0 + (long)(0 * B_ + srow) * H_);
      #pragma unroll
      for (int q = 0; q < 4; q++){
        f32x4 v = p[sl32 + 32 * q];
        u64 pk = (u64)f2h(v[0]) | ((u64)f2h(v[1]) << 16)
               | ((u64)f2h(v[2]) << 32) | ((u64)f2h(v[3]) << 48);
        *(u64*)&P0[srow][4 * (sl32 + 32 * q)] = pk;
      }
    } else if (a0 || a1){
      const u64* p = (const u64*)(h16 + ((long)(0 * T_ + s - 1) * B_ + srow) * H_);
      #pragma unroll
      for (int q = 0; q < 4; q++)
        *(u64*)&P0[srow][4 * (sl32 + 32 * q)] = allc(p + sl32 + 32 * q);
    }
    if (a1 && t1 == 0){
      const f32x4* p = (const f32x4*)(hidden0 + (long)(1 * B_ + srow) * H_);
      #pragma unroll
      for (int q = 0; q < 4; q++){
        f32x4 v = p[sl32 + 32 * q];
        u64 pk = (u64)f2h(v[0]) | ((u64)f2h(v[1]) << 16)
               | ((u64)f2h(v[2]) << 32) | ((u64)f2h(v[3]) << 48);
        *(u64*)&P1[srow][4 * (sl32 + 32 * q)] = pk;
      }
    } else if (a1 || a2){
      const u64* p = (const u64*)(h16 + ((long)(1 * T_ + s - 2) * B_ + srow) * H_);
      #pragma unroll
      for (int q = 0; q < 4; q++)
        *(u64*)&P1[srow][4 * (sl32 + 32 * q)] = allc(p + sl32 + 32 * q);
    }
    if (a2){
      if (t2v == 0){
        const f32x4* p = (const f32x4*)(hidden0 + (long)(2 * B_ + srow) * H_);
        #pragma unroll
        for (int q = 0; q < 4; q++){
          f32x4 v = p[sl32 + 32 * q];
          u64 pk = (u64)f2h(v[0]) | ((u64)f2h(v[1]) << 16)
                 | ((u64)f2h(v[2]) << 32) | ((u64)f2h(v[3]) << 48);
          *(u64*)&P2[srow][4 * (sl32 + 32 * q)] = pk;
        }
      } else {
        const u64* p = (const u64*)(h16 + ((long)(2 * T_ + s - 3) * B_ + srow) * H_);
        #pragma unroll
        for (int q = 0; q < 4; q++)
          *(u64*)&P2[srow][4 * (sl32 + 32 * q)] = allc(p + sl32 + 32 * q);
      }
    }
    __syncthreads();

    // ---- compute dots (per-thread 64-chunk) + wave-local reduce + gate ----
    float A0 = 0, A1 = 0, A2 = 0;
    float Bh0 = 0, Bh1 = 0, Bh2 = 0, Bx0 = 0, Bx1 = 0, Bx2 = 0;
    float Ch0 = 0, Ch1 = 0, Ch2 = 0, Cx0 = 0, Cx1 = 0, Cx2 = 0;
    if (a0){
      const u16* wl = whh_h;
      const h8* w0 = (const h8*)(wl + ((long)(0 * H_ + j)) * H_ + kbase);
      const h8* w1 = (const h8*)(wl + ((long)(1 * H_ + j)) * H_ + kbase);
      const h8* w2 = (const h8*)(wl + ((long)(2 * H_ + j)) * H_ + kbase);
      #pragma unroll 2
      for (int k8 = 0; k8 < 8; k8++){
        h8 hv = *(const h8*)&P0[b][kbase + 8 * k8];
        A0 = dot8h(w0[k8], hv, A0);
        A1 = dot8h(w1[k8], hv, A1);
        A2 = dot8h(w2[k8], hv, A2);
      }
    }
    if (a1){
      const u16* wl = whh_h + (long)1 * 1536 * H_;
      const u16* ul = wih_h + (long)1 * 1536 * H_;
      const h8* w0 = (const h8*)(wl + ((long)(0 * H_ + j)) * H_ + kbase);
      const h8* w1 = (const h8*)(wl + ((long)(1 * H_ + j)) * H_ + kbase);
      const h8* w2 = (const h8*)(wl + ((long)(2 * H_ + j)) * H_ + kbase);
      const h8* u0 = (const h8*)(ul + ((long)(0 * H_ + j)) * H_ + kbase);
      const h8* u1 = (const h8*)(ul + ((long)(1 * H_ + j)) * H_ + kbase);
      const h8* u2 = (const h8*)(ul + ((long)(2 * H_ + j)) * H_ + kbase);
      #pragma unroll 2
      for (int k8 = 0; k8 < 8; k8++){
        h8 hv = *(const h8*)&P1[b][kbase + 8 * k8];
        h8 xv = *(const h8*)&P0[b][kbase + 8 * k8];
        Bh0 = dot8h(w0[k8], hv, Bh0);
        Bh1 = dot8h(w1[k8], hv, Bh1);
        Bh2 = dot8h(w2[k8], hv, Bh2);
        Bx0 = dot8h(u0[k8], xv, Bx0);
        Bx1 = dot8h(u1[k8], xv, Bx1);
        Bx2 = dot8h(u2[k8], xv, Bx2);
      }
    }
    if (a2){
      const u16* wl = whh_h + (long)2 * 1536 * H_;
      const u16* ul = wih_h + (long)2 * 1536 * H_;
      const h8* w0 = (const h8*)(wl + ((long)(0 * H_ + j)) * H_ + kbase);
      const h8* w1 = (const h8*)(wl + ((long)(1 * H_ + j)) * H_ + kbase);
      const h8* w2 = (const h8*)(wl + ((long)(2 * H_ + j)) * H_ + kbase);
      const h8* u0 = (const h8*)(ul + ((long)(0 * H_ + j)) * H_ + kbase);
      const h8* u1 = (const h8*)(ul + ((long)(1 * H_ + j)) * H_ + kbase);
      const h8* u2 = (const h8*)(ul + ((long)(2 * H_ + j)) * H_ + kbase);
      #pragma unroll 2
      for (int k8 = 0; k8 < 8; k8++){
        h8 hv = *(const h8*)&P2[b][kbase + 8 * k8];
        h8 xv = *(const h8*)&P1[b][kbase + 8 * k8];
        Ch0 = dot8h(w0[k8], hv, Ch0);
        Ch1 = dot8h(w1[k8], hv, Ch1);
        Ch2 = dot8h(w2[k8], hv, Ch2);
        Cx0 = dot8h(u0[k8], xv, Cx0);
        Cx1 = dot8h(u1[k8], xv, Cx1);
        Cx2 = dot8h(u2[k8], xv, Cx2);
      }
    }
    #define RED3(v) { v += __shfl_xor(v, 1); v += __shfl_xor(v, 2); v += __shfl_xor(v, 4); }
    if (a0){ RED3(A0) RED3(A1) RED3(A2) }
    if (a1){ RED3(Bh0) RED3(Bh1) RED3(Bh2) RED3(Bx0) RED3(Bx1) RED3(Bx2) }
    if (a2){ RED3(Ch0) RED3(Ch1) RED3(Ch2) RED3(Cx0) RED3(Cx1) RED3(Cx2) }
    #undef RED3

    if (ks == 0){
      if (a0){
        float r = sigmoid_(g0r + A0 + bh00);
        float z = sigmoid_(g1r + A1 + bh01);
        float n = tanh_(g2r + r * (A2 + bh02));
        float h = (1.f - z) * n + z * hp0;
        union { float f; u32 u; } cv; cv.f = h;
        __hip_atomic_store((u32*)(h_all + (long)((0 * T_ + t0) * B_ + b) * H_ + j),
                           cv.u, __ATOMIC_RELAXED, __HIP_MEMORY_SCOPE_AGENT);
        __hip_atomic_store(h16 + ((long)(0 * T_ + t0) * B_ + b) * H_ + j,
                           f2h(h), __ATOMIC_RELAXED, __HIP_MEMORY_SCOPE_AGENT);
      }
      if (a1){
        float r = sigmoid_(Bx0 + bi10 + Bh0 + bh10);
        float z = sigmoid_(Bx1 + bi11 + Bh1 + bh11);
        float n = tanh_(Bx2 + bi12 + r * (Bh2 + bh12));
        float h = (1.f - z) * n + z * hp1;
        union { float f; u32 u; } cv; cv.f = h;
        __hip_atomic_store((u32*)(h_all + (long)((1 * T_ + t1) * B_ + b) * H_ + j),
                           cv.u, __ATOMIC_RELAXED, __HIP_MEMORY_SCOPE_AGENT);
        __hip_atomic_store(h16 + ((long)(1 * T_ + t1) * B_ + b) * H_ + j,
                           f2h(h), __ATOMIC_RELAXED, __HIP_MEMORY_SCOPE_AGENT);
      }
      if (a2){
        float r = sigmoid_(Cx0 + bi20 + Ch0 + bh20);
        float z = sigmoid_(Cx1 + bi21 + Ch1 + bh21);
        float n = tanh_(Cx2 + bi22 + r * (Ch2 + bh22));
        float h = (1.f - z) * n + z * hp2;
        union { float f; u32 u; } cv; cv.f = h;
        __hip_atomic_store((u32*)(h_all + (long)((2 * T_ + t2v) * B_ + b) * H_ + j),
                           cv.u, __ATOMIC_RELAXED, __HIP_MEMORY_SCOPE_AGENT);
        __hip_atomic_store(h16 + ((long)(2 * T_ + t2v) * B_ + b) * H_ + j,
                           f2h(h), __ATOMIC_RELAXED, __HIP_MEMORY_SCOPE_AGENT);
        ch_bf[(long)(b * T_ + t2v) * 1024 + 512 + j] = f2bf(h);
      }
    }
    if (s == T_ + NL_ - 2) break;

    // ---- barrier: distributed relaxed flags, single-wave poll ----
    __syncthreads();                       // drains vmcnt (stores ack'd)
    if (tid == 0)
      __hip_atomic_store(cnt + bx * 16, (u32)(s + 1),
                         __ATOMIC_RELAXED, __HIP_MEMORY_SCOPE_AGENT);
    if (tid < 64){
      long guard = 0;
      while ((__hip_atomic_load(cnt + tid * 16, __ATOMIC_RELAXED, __HIP_MEMORY_SCOPE_AGENT)
                < (u32)(s + 1) ||
              __hip_atomic_load(cnt + (tid + 64) * 16, __ATOMIC_RELAXED, __HIP_MEMORY_SCOPE_AGENT)
                < (u32)(s + 1)) && guard < (1L << 23)){
        __builtin_amdgcn_s_sleep(1);
        guard++;
      }
    }
    __syncthreads();
  }
}

// ---------------- merged tanh-additive scores (src + word) ----------------

__global__ __launch_bounds__(256) void k_scores2(const u16* __restrict__ enc,
    const u16* __restrict__ wp, const float* __restrict__ dec_all,
    const float* __restrict__ av, const float* __restrict__ wv,
    float* __restrict__ aw, float* __restrict__ ra){
  int b = blockIdx.x, y = blockIdx.y, tz = blockIdx.z;
  const u16* ebf; int erpb, doff, et, ldo; const float* vv; float* out;
  if (y < 8){ ebf = enc; erpb = S_;  doff = 0;    vv = av; out = aw; ldo = S_;  et = y; }
  else      { ebf = wp;  erpb = RL_; doff = 1024; vv = wv; out = ra; ldo = RL_; et = y - 8; }
  int tid = threadIdx.x;
  __shared__ float dsh[8][512];
  __shared__ float vsh[512];
  __shared__ float redsv[4];
  for (int i = tid; i < 8 * 128; i += 256){
    int tl = i >> 7, c = (i & 127) << 2;
    *(f32x4*)&dsh[tl][c] =
      *(const f32x4*)(dec_all + ((long)(b * T_) + tz * 8 + tl) * 1536 + doff + c);
  }
  for (int i = tid; i < 128; i += 256)
    *(f32x4*)&vsh[i << 2] = *(const f32x4*)(vv + (i << 2));
  __syncthreads();
  float pvv = vsh[tid] + vsh[tid + 256];
  for (int o = 32; o > 0; o >>= 1) pvv += __shfl_xor(pvv, o);
  if ((tid & 63) == 0) redsv[tid >> 6] = pvv;
  __syncthreads();
  float sumv = redsv[0] + redsv[1] + redsv[2] + redsv[3];

  int el = tid & 63, tq = tid >> 6;
  const u16* erow = ebf + ((long)b * erpb + et * 64 + el) * H_;
  float acc0 = 0.f, acc1 = 0.f;
  for (int h0 = 0; h0 < H_; h0 += 8){
    short8 ev = *(const short8*)(erow + h0);
    float w[8], vq[8];
    #pragma unroll
    for (int q = 0; q < 8; q++) w[q] = bf2f((u16)ev[q]);
    #pragma unroll
    for (int q = 0; q < 8; q++) vq[q] = vsh[h0 + q];
    const float* d0 = &dsh[tq * 2 + 0][h0];
    const float* d1 = &dsh[tq * 2 + 1][h0];
    #pragma unroll
    for (int q = 0; q < 8; q++){
      float e0 = EXP2F(w[q] + d0[q]);
      acc0 += vq[q] * RCPF(e0 + 1.f);
      float e1 = EXP2F(w[q] + d1[q]);
      acc1 += vq[q] * RCPF(e1 + 1.f);
    }
  }
  int eg = et * 64 + el;
  long r0 = (long)(b * T_ + tz * 8 + tq * 2 + 0) * ldo + eg;
  long r1 = (long)(b * T_ + tz * 8 + tq * 2 + 1) * ldo + eg;
  out[r0] = sumv - 2.f * acc0;
  out[r1] = sumv - 2.f * acc1;
}

// ---------------- merged: softmax over S (y=0) + scd/ad (y=1) ----------------

__global__ __launch_bounds__(256) void k_smax_scd(float* __restrict__ aw,
    const float* __restrict__ doc_proj, const float* __restrict__ dec_all,
    const float* __restrict__ hd_v, float* __restrict__ ad){
  int rid = blockIdx.x, tid = threadIdx.x;
  __shared__ float red4[4];
  __shared__ float red8[8][32];
  if (blockIdx.y == 0){
    float* row = aw + (long)rid * S_;
    float x0 = row[tid], x1 = row[tid + 256];
    float m = fmaxf(x0, x1);
    for (int o = 32; o > 0; o >>= 1) m = fmaxf(m, __shfl_xor(m, o));
    if ((tid & 63) == 0) red4[tid >> 6] = m;
    __syncthreads();
    m = fmaxf(fmaxf(red4[0], red4[1]), fmaxf(red4[2], red4[3]));
    float e0 = __expf(x0 - m), e1 = __expf(x1 - m);
    float s = e0 + e1;
    for (int o = 32; o > 0; o >>= 1) s += __shfl_xor(s, o);
    __syncthreads();
    if ((tid & 63) == 0) red4[tid >> 6] = s;
    __syncthreads();
    s = red4[0] + red4[1] + red4[2] + red4[3];
    float inv = 1.f / s;
    row[tid] = e0 * inv; row[tid + 256] = e1 * inv;
  } else {
    int b = rid / T_;
    int r = tid >> 5, kp = tid & 31;
    const float* dp = doc_proj + (long)(b * R_ + r) * H_;
    const float* d  = dec_all + (long)rid * 1536 + 512;
    float s = 0.f;
    for (int h = kp * 16; h < kp * 16 + 16; h++){
      float e = EXP2F(dp[h] + d[h]);
      s += hd_v[h] * (1.f - 2.f * RCPF(e + 1.f));
    }
    red8[r][kp] = s;
    __syncthreads();
    if (tid < 8){
      float sc = 0.f;
      for (int k = 0; k < 32; k++) sc += red8[tid][k];
      red8[tid][0] = sc;
    }
    __syncthreads();
    if (tid == 0){
      float m = -1e30f;
      for (int q = 0; q < 8; q++) m = fmaxf(m, red8[q][0]);
      float e[8], sum = 0.f;
      for (int q = 0; q < 8; q++){ e[q] = __expf(red8[q][0] - m); sum += e[q]; }
      float inv = 1.f / sum;
      for (int q = 0; q < 8; q++) ad[rid * R_ + q] = e[q] * inv;
    }
  }
}

// softmax over L per (rid,r), times ad
__global__ __launch_bounds__(256) void k_aww_ra(float* __restrict__ raBuf,
                                                const float* __restrict__ ad){
  int rid = blockIdx.x, r = blockIdx.y, tid = threadIdx.x;
  float* row = raBuf + (long)rid * RL_ + r * L_;
  float x = row[tid];
  float m = x;
  for (int o = 32; o > 0; o >>= 1) m = fmaxf(m, __shfl_xor(m, o));
  __shared__ float red[4];
  if ((tid & 63) == 0) red[tid >> 6] = m;
  __syncthreads();
  m = fmaxf(fmaxf(red[0], red[1]), fmaxf(red[2], red[3]));
  float e = __expf(x - m);
  float s = e;
  for (int o = 32; o > 0; o >>= 1) s += __shfl_xor(s, o);
  __syncthreads();
  if ((tid & 63) == 0) red[tid >> 6] = s;
  __syncthreads();
  s = red[0] + red[1] + red[2] + red[3];
  row[tid] = (e / s) * ad[rid * R_ + r];
}

// ---------------- unified split-K attention-weighted sums ----------------

__global__ __launch_bounds__(256) void k_awgemm2(const float* __restrict__ aw,
    const float* __restrict__ raBuf, const u16* __restrict__ cwr_bf,
    const u16* __restrict__ rwr_bf, float* __restrict__ pbuf){
  int b = blockIdx.x, ht = blockIdx.y, z = blockIdx.z;
  const float* wts; const u16* Wbuf; float* pdst; int KS, CH, kc;
  if (z < 8){ wts = aw;    Wbuf = cwr_bf; pdst = pbuf;                 KS = S_;  CH = 64;  kc = z; }
  else      { wts = raBuf; Wbuf = rwr_bf; pdst = pbuf + (long)M_ * H_; KS = RL_; CH = 256; kc = z - 8; }
  int tid = threadIdx.x;
  int hl = tid & 63, tq = tid >> 6;
  int h = ht * 256 + hl * 4;
  int base = kc * CH;
  float a[8][4];
  #pragma unroll
  for (int tt = 0; tt < 8; tt++)
    #pragma unroll
    for (int q = 0; q < 4; q++) a[tt][q] = 0.f;
  const float* wrow = wts + ((long)(b * T_) + tq * 8) * KS + base;
  for (int sl = 0; sl < CH; sl++){
    const u16* wp = Wbuf + ((long)b * KS + base + sl) * H_ + h;
    u32 p0 = *(const u32*)(wp);
    u32 p1 = *(const u32*)(wp + 2);
    float v0 = bf2f((u16)(p0 & 0xffff)), v1 = bf2f((u16)(p0 >> 16));
    float v2 = bf2f((u16)(p1 & 0xffff)), v3 = bf2f((u16)(p1 >> 16));
    #pragma unroll
    for (int tt = 0; tt < 8; tt++){
      float w = wrow[(long)tt * KS + sl];
      a[tt][0] += w * v0; a[tt][1] += w * v1;
      a[tt][2] += w * v2; a[tt][3] += w * v3;
    }
  }
  #pragma unroll
  for (int tt = 0; tt < 8; tt++){
    long o = (long)kc * (2 * M_ * H_) + ((long)(b * T_ + tq * 8 + tt)) * H_ + h;
    *(f32x4*)(pdst + o) = (f32x4){a[tt][0], a[tt][1], a[tt][2], a[tt][3]};
  }
}

__global__ __launch_bounds__(256) void k_red8(const float* __restrict__ pbuf,
                                              float* __restrict__ outp){
  long n = 2L * M_ * H_;
  long i = (long)blockIdx.x * 256 + threadIdx.x;
  if (i >= n) return;
  float s = 0.f;
  #pragma unroll
  for (int kc = 0; kc < 8; kc++) s += pbuf[(long)kc * n + i];
  outp[i] = s;
}

// ---------------- fused gate + pgen ----------------

__global__ __launch_bounds__(256) void k_gatepgen(const float* __restrict__ ctx,
    const float* __restrict__ rctx, const float* __restrict__ gate_w,
    const float* __restrict__ gate_b, float* __restrict__ contexts,
    u16* __restrict__ ch_bf, const float* __restrict__ h_all,
    const u16* __restrict__ x_bf, const float* __restrict__ pgen_w,
    const float* __restrict__ pgen_b, float* __restrict__ pg){
  int rid = blockIdx.x, tid = threadIdx.x;
  int b = rid / T_, t = rid % T_;
  const float* c  = ctx  + (long)rid * H_;
  const float* rc = rctx + (long)rid * H_;
  float part = 0.f;
  for (int h = tid; h < H_; h += 256) part += c[h] * gate_w[h] + rc[h] * gate_w[H_ + h];
  for (int o = 32; o > 0; o >>= 1) part += __shfl_xor(part, o);
  __shared__ float red[4];
  if ((tid & 63) == 0) red[tid >> 6] = part;
  __syncthreads();
  float g = sigmoid_(red[0] + red[1] + red[2] + red[3] + gate_b[0]);
  for (int h = tid; h < H_; h += 256){
    float v = g * c[h] + (1.f - g) * rc[h];
    contexts[(long)rid * H_ + h] = v;
    ch_bf[(long)rid * 1024 + h] = f2bf(v);
  }
  float p0 = 0.f, p1 = 0.f, p2 = 0.f;
  for (int k = tid; k < 1536; k += 256){
    float v;
    if (k < 512)       v = g * c[k] + (1.f - g) * rc[k];
    else if (k < 1024) v = h_all[((2 * T_ + t) * B_ + b) * H_ + (k - 512)];
    else               v = bf2f(x_bf[(long)rid * H_ + (k - 1024)]);
    p0 += v * pgen_w[k * 3 + 0];
    p1 += v * pgen_w[k * 3 + 1];
    p2 += v * pgen_w[k * 3 + 2];
  }
  for (int o = 32; o > 0; o >>= 1){
    p0 += __shfl_xor(p0, o); p1 += __shfl_xor(p1, o); p2 += __shfl_xor(p2, o);
  }
  __shared__ float r0[4], r1[4], r2[4];
  if ((tid & 63) == 0){ r0[tid >> 6] = p0; r1[tid >> 6] = p1; r2[tid >> 6] = p2; }
  __syncthreads();
  if (tid == 0){
    p0 = r0[0]+r0[1]+r0[2]+r0[3] + pgen_b[0];
    p1 = r1[0]+r1[1]+r1[2]+r1[3] + pgen_b[1];
    p2 = r2[0]+r2[1]+r2[2]+r2[3] + pgen_b[2];
    float m = fmaxf(p0, fmaxf(p1, p2));
    float e0 = __expf(p0 - m), e1 = __expf(p1 - m), e2 = __expf(p2 - m);
    float inv = 1.f / (e0 + e1 + e2);
    pg[rid * 3 + 0] = e0 * inv;
    pg[rid * 3 + 1] = e1 * inv;
    pg[rid * 3 + 2] = e2 * inv;
  }
}

// ---------------- final assembly ----------------

__global__ __launch_bounds__(256) void k_final_vocab(float* __restrict__ fin,
    const float* __restrict__ pm, const float* __restrict__ ps,
    const float* __restrict__ pg){
  int rid = blockIdx.y, tid = threadIdx.x;
  const float* mrow = pm + (long)rid * 392;
  const float* srow = ps + (long)rid * 392;
  float m = -1e30f, s = 0.f;
  for (int q = tid; q < 391; q += 256){
    float m2 = mrow[q], s2 = srow[q];
    float M = fmaxf(m, m2);
    s = s * __expf(m - M) + s2 * __expf(m2 - M);
    m = M;
  }
  for (int o = 32; o > 0; o >>= 1){
    float m2 = __shfl_xor(m, o), s2 = __shfl_xor(s, o);
    float M = fmaxf(m, m2);
    s = s * __expf(m - M) + s2 * __expf(m2 - M);
    m = M;
  }
  __shared__ float rm[4], rs[4], fm, fs;
  if ((tid & 63) == 0){ rm[tid >> 6] = m; rs[tid >> 6] = s; }
  __syncthreads();
  if (tid == 0){
    float Mx = rm[0], Sx = rs[0];
    for (int q = 1; q < 4; q++){
      float M2 = fmaxf(Mx, rm[q]);
      Sx = Sx * __expf(Mx - M2) + rs[q] * __expf(rm[q] - M2);
      Mx = M2;
    }
    fm = Mx; fs = Sx;
  }
  __syncthreads();
  float mx = fm;
  float scale = pg[rid * 3 + 0] / fs;
  int v = (blockIdx.x * 256 + tid) * 2;
  if (v >= FINW) return;
  long base = (long)rid * FINW;
  if (v + 1 < V_){
    float2* p = (float2*)(fin + base + v);
    float2 x = *p;
    x.x = __expf(x.x - mx) * scale;
    x.y = __expf(x.y - mx) * scale;
    *p = x;
  } else {
    for (int q = 0; q < 2 && v + q < FINW; q++){
      float x = fin[base + v + q];
      fin[base + v + q] = (v + q < V_) ? __expf(x - mx) * scale : 0.f;
    }
  }
}

__global__ __launch_bounds__(512) void k_scatter(float* __restrict__ fin,
    const float* __restrict__ aw, const float* __restrict__ raBuf,
    const float* __restrict__ pg, const int* __restrict__ src_oov,
    const int* __restrict__ ref_oovs){
  int rid = blockIdx.x, tid = threadIdx.x;
  int b = rid / T_;
  if (tid < 256){
    float p1 = pg[rid * 3 + 1];
    for (int s = tid; s < S_; s += 256){
      float val = p1 * aw[(long)rid * S_ + s];
      int idx = src_oov[b * S_ + s];
      atomicAdd(fin + (long)rid * FINW + idx, val);
    }
  } else {
    int t2 = tid - 256;
    float p2 = pg[rid * 3 + 2];
    for (int i = t2; i < RL_; i += 256){
      float val = p2 * raBuf[(long)rid * RL_ + i];
      int idx = ref_oovs[b * RL_ + i];
      atomicAdd(fin + (long)rid * FINW + idx, val);
    }
  }
}

// ---------------- host ----------------

extern "C" void kernel_launch(void* const* d_in, const int* in_sizes, int n_in,
                              void* d_out, int out_size, void* d_ws, size_t ws_size,
                              hipStream_t stream)
{
  (void)in_sizes; (void)n_in; (void)out_size;
  const int*   tokens   = (const int*)  d_in[0];
  const int*   src_oov  = (const int*)  d_in[1];
  const int*   ref_oovs = (const int*)  d_in[2];
  const float* cwr      = (const float*)d_in[7];
  const float* rwr      = (const float*)d_in[8];
  const float* rdr      = (const float*)d_in[9];
  const float* hidden0  = (const float*)d_in[10];
  const float* embed_w  = (const float*)d_in[11];
  const float* gru_wih  = (const float*)d_in[12];
  const float* gru_whh  = (const float*)d_in[13];
  const float* gru_bih  = (const float*)d_in[14];
  const float* gru_bhh  = (const float*)d_in[15];
  const float* attn_Wd  = (const float*)d_in[16];
  const float* attn_We  = (const float*)d_in[17];
  const float* attn_v   = (const float*)d_in[18];
  const float* hd_Wd    = (const float*)d_in[19];
  const float* hd_We    = (const float*)d_in[20];
  const float* hd_v     = (const float*)d_in[21];
  const float* hw_Wd    = (const float*)d_in[22];
  const float* hw_We    = (const float*)d_in[23];
  const float* hw_v     = (const float*)d_in[24];
  const float* gate_w   = (const float*)d_in[25];
  const float* gate_b   = (const float*)d_in[26];
  const float* fc_w     = (const float*)d_in[27];
  const float* fc_b     = (const float*)d_in[28];
  const float* out_w    = (const float*)d_in[29];
  const float* out_b    = (const float*)d_in[30];
  const float* pgen_w   = (const float*)d_in[31];
  const float* pgen_b   = (const float*)d_in[32];

  float* fin = (float*)d_out;                      // [M_][FINW]
  float* aw  = fin + (long)M_ * FINW;              // [M_][S_] attn_dists output

  char* wptr = (char*)d_ws;
  auto alloc = [&](size_t nbytes) -> void* {
    void* p = (void*)wptr;
    wptr += (nbytes + 255) & ~(size_t)255;
    return p;
  };
  float* gx0      = (float*)alloc((size_t)M_ * 1536 * 4);
  float* h_all    = (float*)alloc((size_t)NL_ * T_ * B_ * H_ * 4);
  float* dec_all  = (float*)alloc((size_t)M_ * 1536 * 4);
  float* raBuf    = (float*)alloc((size_t)M_ * RL_ * 4);
  float* ad       = (float*)alloc((size_t)M_ * R_ * 4);
  float* ctx      = (float*)alloc((size_t)M_ * H_ * 4);   // ctx,rctx contiguous
  float* rctx     = (float*)alloc((size_t)M_ * H_ * 4);
  float* contexts = (float*)alloc((size_t)M_ * H_ * 4);
  float* pg       = (float*)alloc((size_t)M_ * 3 * 4);
  float* pm       = (float*)alloc((size_t)M_ * 392 * 4);
  float* ps       = (float*)alloc((size_t)M_ * 392 * 4);
  float* doc_proj = (float*)alloc((size_t)B_ * R_ * H_ * 4);
  float* pbuf     = (float*)alloc((size_t)8 * 2 * M_ * H_ * 4);
  unsigned int* gru_cnt = (unsigned int*)alloc((GRUB + NCONV) * 16 * 4);
  u16* h16        = (u16*)alloc((size_t)NL_ * T_ * B_ * H_ * 2);
  u16* x_bf       = (u16*)alloc((size_t)M_ * H_ * 2);
  u16* ch_bf      = (u16*)alloc((size_t)M_ * 1024 * 2);
  u16* whh_h16    = (u16*)alloc((size_t)NL_ * 1536 * H_ * 2);
  u16* wih_h16    = (u16*)alloc((size_t)NL_ * 1536 * H_ * 2);
  u16* wih0_bf    = (u16*)alloc((size_t)1536 * H_ * 2);
  u16* WT         = (u16*)alloc((size_t)6 * H_ * H_ * 2);  // [We x3 | Wd x3]
  u16* fcwT       = (u16*)alloc((size_t)H_ * 1024 * 2);
  u16* fcout_bf   = (u16*)alloc((size_t)M_ * H_ * 2);
  u16* cwr_bf     = (u16*)alloc((size_t)B_ * S_ * H_ * 2);
  u16* enc_bf     = (u16*)alloc((size_t)B_ * S_ * H_ * 2);
  u16* rwr_bf     = (u16*)alloc((size_t)B_ * RL_ * H_ * 2);
  u16* wp_bf      = (u16*)alloc((size_t)B_ * RL_ * H_ * 2);
  u16* rdr_bf     = (u16*)alloc((size_t)B_ * R_ * H_ * 2);
  u16* outwT_ded  = (u16*)alloc((size_t)V_ * H_ * 2);      // 51.2MB, only if ws permits
  bool big = ((char*)outwT_ded + (size_t)V_ * H_ * 2) <= ((char*)d_ws + ws_size);
  u16* outwT = big ? outwT_ded : rwr_bf;   // fallback: alias (dead after awgemm)
  int nshadow = big ? NCONV : 0;

  hipMemsetAsync(gru_cnt, 0, (GRUB + NCONV) * 16 * 4, stream);

  // --- host conversions ---
  k_embed<<<M_, 256, 0, stream>>>(tokens, embed_w, x_bf);
  {
    CJ j0{cwr, cwr_bf, (long)B_ * S_ * H_, 0};
    CJ j1{rwr, rwr_bf, (long)B_ * RL_ * H_, 0};
    CJ j2{gru_whh, whh_h16, (long)NL_ * 1536 * H_, 1};
    CJ j3{gru_wih, wih_h16, (long)NL_ * 1536 * H_, 1};
    CJ j4{rdr, rdr_bf, (long)B_ * R_ * H_, 0};
    CJ j5{gru_wih, wih0_bf, (long)1536 * H_, 0};
    k_conv6<<<dim3(512, 6), 256, 0, stream>>>(j0, j1, j2, j3, j4, j5);
  }
  k_convT6<<<dim3(16, 16, 6), 256, 0, stream>>>(attn_We, hd_We, hw_We,
                                                attn_Wd, hd_Wd, hw_Wd, WT);
  k_convT<<<dim3(16, 32), 256, 0, stream>>>(fc_w, 1024, H_, fcwT);

  // --- gx0 = x @ wih0^T + bih0 ---
  k_gemm_nt<<<dim3(4, 12), 256, 0, stream>>>(x_bf, H_, wih0_bf, H_, gru_bih,
                                             (void*)gx0, 1536, 1536, H_, 0, 1.f);
  if (!big){
    k_gemm_nt<<<dim3(64, 4), 256, 0, stream>>>(cwr_bf, H_, WT, H_, (const float*)0,
                                               (void*)enc_bf, H_, H_, H_, 1, S2C);
    k_gemm_nt<<<dim3(256, 4), 256, 0, stream>>>(rwr_bf, H_, WT + 2 * H_ * H_, H_, (const float*)0,
                                                (void*)wp_bf, H_, H_, H_, 1, S2C);
    k_gemm_nt<<<dim3(1, 4), 256, 0, stream>>>(rdr_bf, H_, WT + H_ * H_, H_, (const float*)0,
                                              (void*)doc_proj, H_, H_, H_, 0, S2C);
  }

  // --- mega kernel ---
  k_gru_mega<<<GRUB + nshadow, 512, 0, stream>>>(gx0, wih_h16, whh_h16, gru_bih, gru_bhh,
                                                 hidden0, h_all, h16, ch_bf, gru_cnt,
                                                 out_w, outwT, cwr_bf, rwr_bf, rdr_bf,
                                                 WT, enc_bf, wp_bf, doc_proj, big ? 1 : 0);

  // dec projections (stacked, scaled)
  k_gemm_nt<<<dim3(4, 12), 256, 0, stream>>>(ch_bf + 512, 1024, WT + 3 * H_ * H_, H_,
                                             (const float*)0, (void*)dec_all, 1536, 1536, H_, 0, S2C);

  // --- attention ---
  k_scores2<<<dim3(16, 40, 4), 256, 0, stream>>>(enc_bf, wp_bf, dec_all, attn_v, hw_v, aw, raBuf);
  k_smax_scd<<<dim3(M_, 2), 256, 0, stream>>>(aw, doc_proj, dec_all, hd_v, ad);
  k_aww_ra<<<dim3(M_, R_), 256, 0, stream>>>(raBuf, ad);

  // --- ctx / rctx via split-K streaming ---
  k_awgemm2<<<dim3(B_, 2, 16), 256, 0, stream>>>(aw, raBuf, cwr_bf, rwr_bf, pbuf);
  if (!big)
    k_convT<<<dim3(1563, 16), 256, 0, stream>>>(out_w, H_, V_, outwT);
  k_red8<<<(2 * M_ * H_ + 255) / 256, 256, 0, stream>>>(pbuf, ctx);

  k_gatepgen<<<M_, 256, 0, stream>>>(ctx, rctx, gate_w, gate_b, contexts, ch_bf,
                                     h_all, x_bf, pgen_w, pgen_b, pg);

  // --- output head ---
  k_gemm_nt<<<dim3(4, 4), 256, 0, stream>>>(ch_bf, 1024, fcwT, 1024, fc_b,
                                            (void*)fcout_bf, H_, H_, 1024, 1, 1.f);
  k_gemm_out<<<dim3(4, 391), 256, 0, stream>>>(fcout_bf, outwT, out_b, fin, pm, ps);
  k_final_vocab<<<dim3(98, M_), 256, 0, stream>>>(fin, pm, ps, pg);
  k_scatter<<<M_, 512, 0, stream>>>(fin, aw, raBuf, pg, src_oov, ref_oovs);
}

// Round 12
// 1117.779 us; speedup vs baseline: 1.5692x; 1.5692x over previous
//
#include <hip/hip_runtime.h>
#include <hip/hip_bf16.h>

// GraphRNNSeq2SeqDecoder — MI355X implementation.
// R12: revert R11's bank-conflicted wave-local GRU (5.2M LDS conflicts) to the
// proven R10 inner loop (dedup 3 panels, LDS red reduction, 192-thread gate),
// with R9's shadow scope (proj GEMMs + out_w transpose only; conv host-side)
// and R10's launch fusions (awgemm2, fused final_vocab, fused scatter).

#define B_   16
#define T_   32
#define S_   512
#define R_   8
#define L_   256
#define RL_  2048
#define H_   512
#define V_   50000
#define NL_  3
#define OOV_ 50
#define M_   512
#define FINW 50050
#define S2C  2.8853900817779268f   // 2*log2(e)
#define GRUB 128
#define NCONV 128
#define HP16 520

typedef __attribute__((ext_vector_type(8))) short    short8;
typedef __attribute__((ext_vector_type(4))) float    f32x4;
typedef __attribute__((ext_vector_type(2))) _Float16 h2;
typedef __attribute__((ext_vector_type(8))) _Float16 h8;
typedef unsigned short u16;
typedef unsigned int   u32;
typedef unsigned long long u64;

#if __has_builtin(__builtin_amdgcn_exp2f)
#define EXP2F __builtin_amdgcn_exp2f
#else
#define EXP2F exp2f
#endif
#if __has_builtin(__builtin_amdgcn_rcpf)
#define RCPF __builtin_amdgcn_rcpf
#else
#define RCPF(x) (1.f/(x))
#endif

__device__ __forceinline__ float bf2f(u16 u){
  union { u32 i; float f; } v; v.i = ((u32)u) << 16; return v.f;
}
__device__ __forceinline__ u16 f2bf(float f){
  union { float f; u32 i; } v; v.f = f;
  return (u16)((v.i + 0x7FFFu + ((v.i >> 16) & 1u)) >> 16);   // RNE
}
__device__ __forceinline__ u16 f2h(float f){
  union { _Float16 h; u16 u; } v; v.h = (_Float16)f; return v.u;
}
__device__ __forceinline__ float tanh_(float x){
  float e = __expf(2.f * x);
  return 1.f - 2.f / (e + 1.f);
}
__device__ __forceinline__ float sigmoid_(float x){
  return 1.f / (1.f + __expf(-x));
}
__device__ __forceinline__ float dot8h(h8 w, h8 x, float acc){
#if __has_builtin(__builtin_amdgcn_fdot2)
  acc = __builtin_amdgcn_fdot2((h2){w[0], w[1]}, (h2){x[0], x[1]}, acc, false);
  acc = __builtin_amdgcn_fdot2((h2){w[2], w[3]}, (h2){x[2], x[3]}, acc, false);
  acc = __builtin_amdgcn_fdot2((h2){w[4], w[5]}, (h2){x[4], x[5]}, acc, false);
  acc = __builtin_amdgcn_fdot2((h2){w[6], w[7]}, (h2){x[6], x[7]}, acc, false);
#else
  #pragma unroll
  for (int q = 0; q < 8; q++) acc += (float)w[q] * (float)x[q];
#endif
  return acc;
}
__device__ __forceinline__ u64 allc(const u64* p){
  return __hip_atomic_load(p, __ATOMIC_RELAXED, __HIP_MEMORY_SCOPE_AGENT);
}
__device__ __forceinline__ float allcf(const float* p){
  u32 v = __hip_atomic_load((const u32*)p, __ATOMIC_RELAXED, __HIP_MEMORY_SCOPE_AGENT);
  union { u32 i; float f; } c; c.i = v; return c.f;
}

// ---------------- conversions ----------------

__global__ __launch_bounds__(256) void k_embed(const int* __restrict__ tokens,
                                               const float* __restrict__ embed_w,
                                               u16* __restrict__ x_bf){
  int rid = blockIdx.x;
  long tok = (long)tokens[rid];
  const float* src = embed_w + tok * H_;
  u16* dst = x_bf + (long)rid * H_;
  for (int e = threadIdx.x; e < H_; e += 256) dst[e] = f2bf(src[e]);
}

struct CJ { const float* s; u16* d; long n; int f16; };

__global__ __launch_bounds__(256) void k_conv6(CJ j0, CJ j1, CJ j2, CJ j3, CJ j4, CJ j5){
  int y = blockIdx.y;
  CJ j = (y == 0) ? j0 : (y == 1) ? j1 : (y == 2) ? j2 : (y == 3) ? j3 : (y == 4) ? j4 : j5;
  long n4 = j.n >> 2;
  long i = (long)blockIdx.x * 256 + threadIdx.x;
  long stride = (long)gridDim.x * 256;
  if (j.f16){
    for (; i < n4; i += stride){
      f32x4 v = *(const f32x4*)(j.s + 4 * i);
      u64 p = (u64)f2h(v[0]) | ((u64)f2h(v[1]) << 16)
            | ((u64)f2h(v[2]) << 32) | ((u64)f2h(v[3]) << 48);
      *(u64*)(j.d + 4 * i) = p;
    }
  } else {
    for (; i < n4; i += stride){
      f32x4 v = *(const f32x4*)(j.s + 4 * i);
      u64 p = (u64)f2bf(v[0]) | ((u64)f2bf(v[1]) << 16)
            | ((u64)f2bf(v[2]) << 32) | ((u64)f2bf(v[3]) << 48);
      *(u64*)(j.d + 4 * i) = p;
    }
  }
}

// dst[c][r] = bf16(src[r][c])
__global__ __launch_bounds__(256) void k_convT(const float* __restrict__ src, int Rr, int Cc,
                                               u16* __restrict__ dst){
  __shared__ float tile[32][33];
  int c0 = blockIdx.x * 32, r0 = blockIdx.y * 32;
  int tx = threadIdx.x & 31, ty = threadIdx.x >> 5;
  for (int i = ty; i < 32; i += 8){
    int r = r0 + i, c = c0 + tx;
    tile[i][tx] = (r < Rr && c < Cc) ? src[(long)r * Cc + c] : 0.f;
  }
  __syncthreads();
  for (int i = ty; i < 32; i += 8){
    int c = c0 + i, r = r0 + tx;
    if (c < Cc && r < Rr) dst[(long)c * Rr + r] = f2bf(tile[tx][i]);
  }
}

__global__ __launch_bounds__(256) void k_convT6(const float* s0, const float* s1,
    const float* s2, const float* s3, const float* s4, const float* s5,
    u16* __restrict__ dstb){
  int z = blockIdx.z;
  const float* src = (z == 0) ? s0 : (z == 1) ? s1 : (z == 2) ? s2
                   : (z == 3) ? s3 : (z == 4) ? s4 : s5;
  u16* dst = dstb + (long)z * H_ * H_;
  __shared__ float tile[32][33];
  int c0 = blockIdx.x * 32, r0 = blockIdx.y * 32;
  int tx = threadIdx.x & 31, ty = threadIdx.x >> 5;
  for (int i = ty; i < 32; i += 8)
    tile[i][tx] = src[(long)(r0 + i) * H_ + c0 + tx];
  __syncthreads();
  for (int i = ty; i < 32; i += 8)
    dst[(long)(c0 + i) * H_ + r0 + tx] = f2bf(tile[tx][i]);
}

// ---------------- bf16 MFMA GEMM tile (device fn; no syncthreads) ----------------

__device__ void dev_gemm_tile(const u16* __restrict__ A, int lda,
                              const u16* __restrict__ W, int ldw,
                              const float* __restrict__ bias,
                              void* __restrict__ Cv, long ldc,
                              int N, int K, int c_bf16, float cscale,
                              int bx, int by, int t256){
  int wave = t256 >> 6, lane = t256 & 63;
  int m0 = bx * 128 + (wave >> 1) * 64;
  int n0 = by * 128 + (wave & 1) * 64;
  int lr = lane & 15, lk = (lane >> 4) * 8;
  f32x4 acc[4][4];
  #pragma unroll
  for (int i = 0; i < 4; i++)
    #pragma unroll
    for (int j = 0; j < 4; j++) acc[i][j] = (f32x4){0.f, 0.f, 0.f, 0.f};

  short8 a0[4], b0[4];
  #pragma unroll
  for (int i = 0; i < 4; i++)
    a0[i] = *(const short8*)(A + (long)(m0 + i * 16 + lr) * lda + lk);
  #pragma unroll
  for (int j = 0; j < 4; j++){
    int c = n0 + j * 16 + lr;
    b0[j] = (c < N) ? *(const short8*)(W + (long)c * ldw + lk) : (short8){0,0,0,0,0,0,0,0};
  }
  for (int k0 = 0; k0 < K; k0 += 32){
    short8 a1[4], b1[4];
    if (k0 + 32 < K){
      int kn = k0 + 32 + lk;
      #pragma unroll
      for (int i = 0; i < 4; i++)
        a1[i] = *(const short8*)(A + (long)(m0 + i * 16 + lr) * lda + kn);
      #pragma unroll
      for (int j = 0; j < 4; j++){
        int c = n0 + j * 16 + lr;
        b1[j] = (c < N) ? *(const short8*)(W + (long)c * ldw + kn) : (short8){0,0,0,0,0,0,0,0};
      }
    }
    #pragma unroll
    for (int i = 0; i < 4; i++)
      #pragma unroll
      for (int j = 0; j < 4; j++)
        acc[i][j] = __builtin_amdgcn_mfma_f32_16x16x32_bf16(a0[i], b0[j], acc[i][j], 0, 0, 0);
    #pragma unroll
    for (int i = 0; i < 4; i++) a0[i] = a1[i];
    #pragma unroll
    for (int j = 0; j < 4; j++) b0[j] = b1[j];
  }
  int rr = (lane >> 4) * 4;                 // C/D: col = lane&15, row = (lane>>4)*4 + e
  #pragma unroll
  for (int j = 0; j < 4; j++){
    int c = n0 + j * 16 + lr;
    if (c >= N) continue;
    float bv = bias ? bias[c] : 0.f;
    #pragma unroll
    for (int i = 0; i < 4; i++){
      #pragma unroll
      for (int e = 0; e < 4; e++){
        long r = m0 + i * 16 + rr + e;
        float v = fmaf(acc[i][j][e], cscale, bv);
        if (c_bf16) ((u16*)Cv)[r * ldc + c] = f2bf(v);
        else        ((float*)Cv)[r * ldc + c] = v;
      }
    }
  }
}

__global__ __launch_bounds__(256) void k_gemm_nt(const u16* __restrict__ A, int lda,
                                                 const u16* __restrict__ W, int ldw,
                                                 const float* __restrict__ bias,
                                                 void* __restrict__ Cv, long ldc,
                                                 int N, int K, int c_bf16, float cscale){
  dev_gemm_tile(A, lda, W, ldw, bias, Cv, ldc, N, K, c_bf16, cscale,
                blockIdx.x, blockIdx.y, threadIdx.x);
}

// ---------------- out-GEMM: logits + LDS epilogue + pm/ps ----------------

__global__ __launch_bounds__(256) void k_gemm_out(const u16* __restrict__ A,
    const u16* __restrict__ W, const float* __restrict__ bias,
    float* __restrict__ fin, float* __restrict__ pm, float* __restrict__ ps){
  const int N = V_;
  __shared__ float cbuf[128][132];
  __shared__ float smx[128][2], ssx[128][2];
  int tid = threadIdx.x;
  int wave = tid >> 6, lane = tid & 63;
  int mb = blockIdx.x * 128, nb = blockIdx.y * 128;
  int m0 = mb + (wave >> 1) * 64;
  int n0 = nb + (wave & 1) * 64;
  int lr = lane & 15, lk = (lane >> 4) * 8;
  f32x4 acc[4][4];
  #pragma unroll
  for (int i = 0; i < 4; i++)
    #pragma unroll
    for (int j = 0; j < 4; j++) acc[i][j] = (f32x4){0.f, 0.f, 0.f, 0.f};

  short8 a0[4], b0[4];
  #pragma unroll
  for (int i = 0; i < 4; i++)
    a0[i] = *(const short8*)(A + (long)(m0 + i * 16 + lr) * 512 + lk);
  #pragma unroll
  for (int j = 0; j < 4; j++){
    int c = n0 + j * 16 + lr;
    b0[j] = (c < N) ? *(const short8*)(W + (long)c * 512 + lk) : (short8){0,0,0,0,0,0,0,0};
  }
  for (int k0 = 0; k0 < 512; k0 += 32){
    short8 a1[4], b1[4];
    if (k0 + 32 < 512){
      int kn = k0 + 32 + lk;
      #pragma unroll
      for (int i = 0; i < 4; i++)
        a1[i] = *(const short8*)(A + (long)(m0 + i * 16 + lr) * 512 + kn);
      #pragma unroll
      for (int j = 0; j < 4; j++){
        int c = n0 + j * 16 + lr;
        b1[j] = (c < N) ? *(const short8*)(W + (long)c * 512 + kn) : (short8){0,0,0,0,0,0,0,0};
      }
    }
    #pragma unroll
    for (int i = 0; i < 4; i++)
      #pragma unroll
      for (int j = 0; j < 4; j++)
        acc[i][j] = __builtin_amdgcn_mfma_f32_16x16x32_bf16(a0[i], b0[j], acc[i][j], 0, 0, 0);
    #pragma unroll
    for (int i = 0; i < 4; i++) a0[i] = a1[i];
    #pragma unroll
    for (int j = 0; j < 4; j++) b0[j] = b1[j];
  }
  int rr = (lane >> 4) * 4;
  int rloc0 = (wave >> 1) * 64, cloc0 = (wave & 1) * 64;
  #pragma unroll
  for (int j = 0; j < 4; j++){
    int c = n0 + j * 16 + lr;
    float bv = (c < N) ? bias[c] : 0.f;
    #pragma unroll
    for (int i = 0; i < 4; i++){
      #pragma unroll
      for (int e = 0; e < 4; e++)
        cbuf[rloc0 + i * 16 + rr + e][cloc0 + j * 16 + lr] = acc[i][j][e] + bv;
    }
  }
  __syncthreads();
  int rl = tid >> 1, ch = tid & 1;
  int cbase = ch * 64;
  int cg = nb + cbase;
  long gbase = (long)(mb + rl) * FINW + cg;
  float mp = -1e30f;
  #pragma unroll 8
  for (int k = 0; k < 64; k += 2){
    float x0 = cbuf[rl][cbase + k], x1 = cbuf[rl][cbase + k + 1];
    float2 xy; xy.x = x0; xy.y = x1;
    *(float2*)(fin + gbase + k) = xy;
    if (cg + k < N)     mp = fmaxf(mp, x0);
    if (cg + k + 1 < N) mp = fmaxf(mp, x1);
  }
  float sp = 0.f;
  #pragma unroll 8
  for (int k = 0; k < 64; k++){
    if (cg + k < N) sp += __expf(cbuf[rl][cbase + k] - mp);
  }
  smx[rl][ch] = mp; ssx[rl][ch] = sp;
  __syncthreads();
  if (tid < 128){
    float ma = smx[tid][0], mb2 = smx[tid][1];
    float M = fmaxf(ma, mb2);
    float S = ssx[tid][0] * __expf(ma - M) + ssx[tid][1] * __expf(mb2 - M);
    long row = mb + tid;
    pm[row * 392 + blockIdx.y] = M;
    ps[row * 392 + blockIdx.y] = S;
  }
}

// ---------------- mega kernel ----------------
// blocks [0,128): GRU recurrence (R10 core: dedup 3 panels, LDS red, 192-gate).
// blocks [128,256): shadow — proj GEMM tiles, then out_w transpose.

__global__ __launch_bounds__(512) void k_gru_mega(
    const float* __restrict__ gx0, const u16* __restrict__ wih_h,
    const u16* __restrict__ whh_h, const float* __restrict__ bih,
    const float* __restrict__ bhh, const float* __restrict__ hidden0,
    float* __restrict__ h_all, u16* __restrict__ ch_bf, unsigned int* cnt,
    const float* __restrict__ out_w, u16* __restrict__ outwT,
    const u16* __restrict__ cwr_bf, const u16* __restrict__ rwr_bf,
    const u16* __restrict__ rdr_bf, const u16* __restrict__ WT,
    u16* __restrict__ enc_bf, u16* __restrict__ wp_bf,
    float* __restrict__ doc_proj, int do_shadow){
  __shared__ u16 P0[16][HP16], P1[16][HP16], P2[16][HP16];
  __shared__ float red0[8][3][4][16];
  __shared__ float red1[8][6][4][16];
  __shared__ float red2[8][6][4][16];
  __shared__ float tconv[2][32][33];
  int bid = blockIdx.x;
  int tid = threadIdx.x;

  if (bid >= GRUB){
    if (!do_shadow) return;
    int wid = bid - GRUB;
    int half = tid >> 8, t256 = tid & 255;
    int worker = wid * 2 + half;
    // --- proj GEMM tiles (enc 256 | wp 1024 | doc 4) ---
    for (int tile = worker; tile < 1284; tile += 256){
      if (tile < 256)
        dev_gemm_tile(cwr_bf, H_, WT, H_, (const float*)0, (void*)enc_bf, H_,
                      H_, H_, 1, S2C, tile >> 2, tile & 3, t256);
      else if (tile < 1280){
        int t = tile - 256;
        dev_gemm_tile(rwr_bf, H_, WT + 2 * H_ * H_, H_, (const float*)0, (void*)wp_bf, H_,
                      H_, H_, 1, S2C, t >> 2, t & 3, t256);
      } else
        dev_gemm_tile(rdr_bf, H_, WT + H_ * H_, H_, (const float*)0, (void*)doc_proj, H_,
                      H_, H_, 0, S2C, 0, tile - 1280, t256);
    }
    __syncthreads();
    // --- transpose out_w [512][50000] f32 -> outwT [50000][512] bf16 ---
    int sub = half, tx = t256 & 31, ty = t256 >> 5;
    const int NT = 1563 * 16;
    for (int base = wid * 2; base < NT; base += NCONV * 2){
      int tile = base + sub;
      bool act = tile < NT;
      int cx = act ? (tile % 1563) : 0;
      int ry = act ? (tile / 1563) : 0;
      int c0 = cx * 32, r0 = ry * 32;
      if (act){
        for (int i = ty; i < 32; i += 8){
          int c = c0 + tx;
          tconv[sub][i][tx] = (c < V_) ? out_w[(long)(r0 + i) * V_ + c] : 0.f;
        }
      }
      __syncthreads();
      if (act){
        for (int i = ty; i < 32; i += 8){
          int c = c0 + i;
          if (c < V_) outwT[(long)c * H_ + r0 + tx] = f2bf(tconv[sub][tx][i]);
        }
      }
      __syncthreads();
    }
    return;
  }

  int bx = bid;
  int b = tid & 15, jj = (tid >> 4) & 3, ks = tid >> 6;
  int j = bx * 4 + jj;
  int kbase = ks * 64;
  int srow = tid >> 5, sl32 = tid & 31;

  for (int s = 0; s < T_ + NL_ - 1; s++){
    int t0 = s, t1 = s - 1, t2v = s - 2;
    bool a0 = (t0 < T_);
    bool a1 = (t1 >= 0 && t1 < T_);
    bool a2 = (t2v >= 0 && t2v < T_);
    // ---- gate-side prefetch (exact f32 carried state + gx0) ----
    float hpj_r = 0.f, gx_r0 = 0.f, gx_r1 = 0.f, gx_r2 = 0.f;
    if (tid < 192){
      int lz = tid >> 6, b2 = tid & 15, jj2 = (tid >> 4) & 3;
      int j2 = bx * 4 + jj2;
      int tt = s - lz;
      if (tt >= 0 && tt < T_){
        hpj_r = (tt == 0) ? hidden0[(lz * B_ + b2) * H_ + j2]
                          : allcf(h_all + (long)((lz * T_ + tt - 1) * B_ + b2) * H_ + j2);
        if (lz == 0){
          const float* g = gx0 + (long)(b2 * T_ + tt) * 1536 + j2;
          gx_r0 = g[0]; gx_r1 = g[512]; gx_r2 = g[1024];
        }
      }
    }
    // ---- 3 distinct panels: P0=h[0][s-1], P1=h[1][s-2], P2=h[2][s-3] ----
    {
      u64 v;
      #define STAGE(PAN, ROWPTR, ATOMIC)                                         \
        {                                                                        \
          const u64* p = (const u64*)(ROWPTR);                                   \
          _Pragma("unroll")                                                      \
          for (int q = 0; q < 8; q++){                                           \
            v = (ATOMIC) ? allc(p + sl32 + 32 * q) : p[sl32 + 32 * q];           \
            union { u64 w; float f[2]; } uu; uu.w = v;                           \
            union { _Float16 h[2]; u32 u; } pk;                                  \
            pk.h[0] = (_Float16)uu.f[0]; pk.h[1] = (_Float16)uu.f[1];            \
            *(u32*)&PAN[srow][2 * (sl32 + 32 * q)] = pk.u;                       \
          }                                                                      \
        }
      if (a0 && t0 == 0)      STAGE(P0, hidden0 + (long)(0 * B_ + srow) * H_, false)
      else if (a0 || a1)      STAGE(P0, h_all + (long)((0 * T_ + s - 1) * B_ + srow) * H_, true)
      if (a1 && t1 == 0)      STAGE(P1, hidden0 + (long)(1 * B_ + srow) * H_, false)
      else if (a1 || a2)      STAGE(P1, h_all + (long)((1 * T_ + s - 2) * B_ + srow) * H_, true)
      if (a2){
        if (t2v == 0)         STAGE(P2, hidden0 + (long)(2 * B_ + srow) * H_, false)
        else                  STAGE(P2, h_all + (long)((2 * T_ + s - 3) * B_ + srow) * H_, true)
      }
      #undef STAGE
    }
    __syncthreads();

    // ---- compute partial dots: l0-hh:P0, l1-hh:P1 l1-ih:P0, l2-hh:P2 l2-ih:P1 ----
    if (a0){
      const u16* wl = whh_h;
      const h8* w0 = (const h8*)(wl + ((long)(0 * H_ + j)) * H_ + kbase);
      const h8* w1 = (const h8*)(wl + ((long)(1 * H_ + j)) * H_ + kbase);
      const h8* w2 = (const h8*)(wl + ((long)(2 * H_ + j)) * H_ + kbase);
      float s0 = 0.f, s1 = 0.f, s2 = 0.f;
      #pragma unroll 2
      for (int k8 = 0; k8 < 8; k8++){
        h8 hv = *(const h8*)&P0[b][kbase + 8 * k8];
        s0 = dot8h(w0[k8], hv, s0);
        s1 = dot8h(w1[k8], hv, s1);
        s2 = dot8h(w2[k8], hv, s2);
      }
      red0[ks][0][jj][b] = s0; red0[ks][1][jj][b] = s1; red0[ks][2][jj][b] = s2;
    }
    if (a1){
      const u16* wl = whh_h + (long)1 * 1536 * H_;
      const u16* ul = wih_h + (long)1 * 1536 * H_;
      const h8* w0 = (const h8*)(wl + ((long)(0 * H_ + j)) * H_ + kbase);
      const h8* w1 = (const h8*)(wl + ((long)(1 * H_ + j)) * H_ + kbase);
      const h8* w2 = (const h8*)(wl + ((long)(2 * H_ + j)) * H_ + kbase);
      const h8* u0 = (const h8*)(ul + ((long)(0 * H_ + j)) * H_ + kbase);
      const h8* u1 = (const h8*)(ul + ((long)(1 * H_ + j)) * H_ + kbase);
      const h8* u2 = (const h8*)(ul + ((long)(2 * H_ + j)) * H_ + kbase);
      float s0 = 0.f, s1 = 0.f, s2 = 0.f, x0 = 0.f, x1 = 0.f, x2 = 0.f;
      #pragma unroll 2
      for (int k8 = 0; k8 < 8; k8++){
        h8 hv = *(const h8*)&P1[b][kbase + 8 * k8];
        h8 xv = *(const h8*)&P0[b][kbase + 8 * k8];
        s0 = dot8h(w0[k8], hv, s0);
        s1 = dot8h(w1[k8], hv, s1);
        s2 = dot8h(w2[k8], hv, s2);
        x0 = dot8h(u0[k8], xv, x0);
        x1 = dot8h(u1[k8], xv, x1);
        x2 = dot8h(u2[k8], xv, x2);
      }
      red1[ks][0][jj][b] = s0; red1[ks][1][jj][b] = s1; red1[ks][2][jj][b] = s2;
      red1[ks][3][jj][b] = x0; red1[ks][4][jj][b] = x1; red1[ks][5][jj][b] = x2;
    }
    if (a2){
      const u16* wl = whh_h + (long)2 * 1536 * H_;
      const u16* ul = wih_h + (long)2 * 1536 * H_;
      const h8* w0 = (const h8*)(wl + ((long)(0 * H_ + j)) * H_ + kbase);
      const h8* w1 = (const h8*)(wl + ((long)(1 * H_ + j)) * H_ + kbase);
      const h8* w2 = (const h8*)(wl + ((long)(2 * H_ + j)) * H_ + kbase);
      const h8* u0 = (const h8*)(ul + ((long)(0 * H_ + j)) * H_ + kbase);
      const h8* u1 = (const h8*)(ul + ((long)(1 * H_ + j)) * H_ + kbase);
      const h8* u2 = (const h8*)(ul + ((long)(2 * H_ + j)) * H_ + kbase);
      float s0 = 0.f, s1 = 0.f, s2 = 0.f, x0 = 0.f, x1 = 0.f, x2 = 0.f;
      #pragma unroll 2
      for (int k8 = 0; k8 < 8; k8++){
        h8 hv = *(const h8*)&P2[b][kbase + 8 * k8];
        h8 xv = *(const h8*)&P1[b][kbase + 8 * k8];
        s0 = dot8h(w0[k8], hv, s0);
        s1 = dot8h(w1[k8], hv, s1);
        s2 = dot8h(w2[k8], hv, s2);
        x0 = dot8h(u0[k8], xv, x0);
        x1 = dot8h(u1[k8], xv, x1);
        x2 = dot8h(u2[k8], xv, x2);
      }
      red2[ks][0][jj][b] = s0; red2[ks][1][jj][b] = s1; red2[ks][2][jj][b] = s2;
      red2[ks][3][jj][b] = x0; red2[ks][4][jj][b] = x1; red2[ks][5][jj][b] = x2;
    }
    __syncthreads();

    // ---- gate phase: 192 threads, layer = tid>>6 ----
    if (tid < 192){
      int lz = tid >> 6, b2 = tid & 15, jj2 = (tid >> 4) & 3;
      int j2 = bx * 4 + jj2;
      int tt = s - lz;
      if (tt >= 0 && tt < T_){
        float gh[3], gxv[3];
        #pragma unroll
        for (int g = 0; g < 3; g++){
          float a = 0.f, c = 0.f;
          if (lz == 0){
            #pragma unroll
            for (int q = 0; q < 8; q++) a += red0[q][g][jj2][b2];
          } else if (lz == 1){
            #pragma unroll
            for (int q = 0; q < 8; q++){ a += red1[q][g][jj2][b2]; c += red1[q][3 + g][jj2][b2]; }
          } else {
            #pragma unroll
            for (int q = 0; q < 8; q++){ a += red2[q][g][jj2][b2]; c += red2[q][3 + g][jj2][b2]; }
          }
          gh[g] = a + bhh[lz * 1536 + g * H_ + j2];
          if (lz == 0) gxv[g] = (g == 0) ? gx_r0 : (g == 1) ? gx_r1 : gx_r2;
          else         gxv[g] = c + bih[lz * 1536 + g * H_ + j2];
        }
        float r = sigmoid_(gxv[0] + gh[0]);
        float z = sigmoid_(gxv[1] + gh[1]);
        float n = tanh_(gxv[2] + r * gh[2]);
        float h = (1.f - z) * n + z * hpj_r;
        union { float f; u32 u; } cv; cv.f = h;
        __hip_atomic_store((u32*)(h_all + (long)((lz * T_ + tt) * B_ + b2) * H_ + j2),
                           cv.u, __ATOMIC_RELAXED, __HIP_MEMORY_SCOPE_AGENT);
        if (lz == 2) ch_bf[(long)(b2 * T_ + tt) * 1024 + 512 + j2] = f2bf(h);
      }
    }
    if (s == T_ + NL_ - 2) break;

    // ---- barrier: distributed relaxed flags ----
    __syncthreads();                       // drains vmcnt (h stores ack'd)
    if (tid == 0)
      __hip_atomic_store(cnt + bx * 16, (u32)(s + 1),
                         __ATOMIC_RELAXED, __HIP_MEMORY_SCOPE_AGENT);
    if (tid < GRUB){
      long guard = 0;
      while (__hip_atomic_load(cnt + tid * 16, __ATOMIC_RELAXED, __HIP_MEMORY_SCOPE_AGENT)
               < (u32)(s + 1) && guard < (1L << 23)){
        __builtin_amdgcn_s_sleep(1);
        guard++;
      }
    }
    __syncthreads();
  }
}

// ---------------- merged tanh-additive scores (src + word) ----------------

__global__ __launch_bounds__(256) void k_scores2(const u16* __restrict__ enc,
    const u16* __restrict__ wp, const float* __restrict__ dec_all,
    const float* __restrict__ av, const float* __restrict__ wv,
    float* __restrict__ aw, float* __restrict__ ra){
  int b = blockIdx.x, y = blockIdx.y, tz = blockIdx.z;
  const u16* ebf; int erpb, doff, et, ldo; const float* vv; float* out;
  if (y < 8){ ebf = enc; erpb = S_;  doff = 0;    vv = av; out = aw; ldo = S_;  et = y; }
  else      { ebf = wp;  erpb = RL_; doff = 1024; vv = wv; out = ra; ldo = RL_; et = y - 8; }
  int tid = threadIdx.x;
  __shared__ float dsh[8][512];
  __shared__ float vsh[512];
  __shared__ float redsv[4];
  for (int i = tid; i < 8 * 128; i += 256){
    int tl = i >> 7, c = (i & 127) << 2;
    *(f32x4*)&dsh[tl][c] =
      *(const f32x4*)(dec_all + ((long)(b * T_) + tz * 8 + tl) * 1536 + doff + c);
  }
  for (int i = tid; i < 128; i += 256)
    *(f32x4*)&vsh[i << 2] = *(const f32x4*)(vv + (i << 2));
  __syncthreads();
  float pvv = vsh[tid] + vsh[tid + 256];
  for (int o = 32; o > 0; o >>= 1) pvv += __shfl_xor(pvv, o);
  if ((tid & 63) == 0) redsv[tid >> 6] = pvv;
  __syncthreads();
  float sumv = redsv[0] + redsv[1] + redsv[2] + redsv[3];

  int el = tid & 63, tq = tid >> 6;
  const u16* erow = ebf + ((long)b * erpb + et * 64 + el) * H_;
  float acc0 = 0.f, acc1 = 0.f;
  for (int h0 = 0; h0 < H_; h0 += 8){
    short8 ev = *(const short8*)(erow + h0);
    float w[8], vq[8];
    #pragma unroll
    for (int q = 0; q < 8; q++) w[q] = bf2f((u16)ev[q]);
    #pragma unroll
    for (int q = 0; q < 8; q++) vq[q] = vsh[h0 + q];
    const float* d0 = &dsh[tq * 2 + 0][h0];
    const float* d1 = &dsh[tq * 2 + 1][h0];
    #pragma unroll
    for (int q = 0; q < 8; q++){
      float e0 = EXP2F(w[q] + d0[q]);
      acc0 += vq[q] * RCPF(e0 + 1.f);
      float e1 = EXP2F(w[q] + d1[q]);
      acc1 += vq[q] * RCPF(e1 + 1.f);
    }
  }
  int eg = et * 64 + el;
  long r0 = (long)(b * T_ + tz * 8 + tq * 2 + 0) * ldo + eg;
  long r1 = (long)(b * T_ + tz * 8 + tq * 2 + 1) * ldo + eg;
  out[r0] = sumv - 2.f * acc0;
  out[r1] = sumv - 2.f * acc1;
}

// ---------------- merged: softmax over S (y=0) + scd/ad (y=1) ----------------

__global__ __launch_bounds__(256) void k_smax_scd(float* __restrict__ aw,
    const float* __restrict__ doc_proj, const float* __restrict__ dec_all,
    const float* __restrict__ hd_v, float* __restrict__ ad){
  int rid = blockIdx.x, tid = threadIdx.x;
  __shared__ float red4[4];
  __shared__ float red8[8][32];
  if (blockIdx.y == 0){
    float* row = aw + (long)rid * S_;
    float x0 = row[tid], x1 = row[tid + 256];
    float m = fmaxf(x0, x1);
    for (int o = 32; o > 0; o >>= 1) m = fmaxf(m, __shfl_xor(m, o));
    if ((tid & 63) == 0) red4[tid >> 6] = m;
    __syncthreads();
    m = fmaxf(fmaxf(red4[0], red4[1]), fmaxf(red4[2], red4[3]));
    float e0 = __expf(x0 - m), e1 = __expf(x1 - m);
    float s = e0 + e1;
    for (int o = 32; o > 0; o >>= 1) s += __shfl_xor(s, o);
    __syncthreads();
    if ((tid & 63) == 0) red4[tid >> 6] = s;
    __syncthreads();
    s = red4[0] + red4[1] + red4[2] + red4[3];
    float inv = 1.f / s;
    row[tid] = e0 * inv; row[tid + 256] = e1 * inv;
  } else {
    int b = rid / T_;
    int r = tid >> 5, kp = tid & 31;
    const float* dp = doc_proj + (long)(b * R_ + r) * H_;
    const float* d  = dec_all + (long)rid * 1536 + 512;
    float s = 0.f;
    for (int h = kp * 16; h < kp * 16 + 16; h++){
      float e = EXP2F(dp[h] + d[h]);
      s += hd_v[h] * (1.f - 2.f * RCPF(e + 1.f));
    }
    red8[r][kp] = s;
    __syncthreads();
    if (tid < 8){
      float sc = 0.f;
      for (int k = 0; k < 32; k++) sc += red8[tid][k];
      red8[tid][0] = sc;
    }
    __syncthreads();
    if (tid == 0){
      float m = -1e30f;
      for (int q = 0; q < 8; q++) m = fmaxf(m, red8[q][0]);
      float e[8], sum = 0.f;
      for (int q = 0; q < 8; q++){ e[q] = __expf(red8[q][0] - m); sum += e[q]; }
      float inv = 1.f / sum;
      for (int q = 0; q < 8; q++) ad[rid * R_ + q] = e[q] * inv;
    }
  }
}

// softmax over L per (rid,r), times ad
__global__ __launch_bounds__(256) void k_aww_ra(float* __restrict__ raBuf,
                                                const float* __restrict__ ad){
  int rid = blockIdx.x, r = blockIdx.y, tid = threadIdx.x;
  float* row = raBuf + (long)rid * RL_ + r * L_;
  float x = row[tid];
  float m = x;
  for (int o = 32; o > 0; o >>= 1) m = fmaxf(m, __shfl_xor(m, o));
  __shared__ float red[4];
  if ((tid & 63) == 0) red[tid >> 6] = m;
  __syncthreads();
  m = fmaxf(fmaxf(red[0], red[1]), fmaxf(red[2], red[3]));
  float e = __expf(x - m);
  float s = e;
  for (int o = 32; o > 0; o >>= 1) s += __shfl_xor(s, o);
  __syncthreads();
  if ((tid & 63) == 0) red[tid >> 6] = s;
  __syncthreads();
  s = red[0] + red[1] + red[2] + red[3];
  row[tid] = (e / s) * ad[rid * R_ + r];
}

// ---------------- unified split-K attention-weighted sums ----------------

__global__ __launch_bounds__(256) void k_awgemm2(const float* __restrict__ aw,
    const float* __restrict__ raBuf, const u16* __restrict__ cwr_bf,
    const u16* __restrict__ rwr_bf, float* __restrict__ pbuf){
  int b = blockIdx.x, ht = blockIdx.y, z = blockIdx.z;
  const float* wts; const u16* Wbuf; float* pdst; int KS, CH, kc;
  if (z < 8){ wts = aw;    Wbuf = cwr_bf; pdst = pbuf;                 KS = S_;  CH = 64;  kc = z; }
  else      { wts = raBuf; Wbuf = rwr_bf; pdst = pbuf + (long)M_ * H_; KS = RL_; CH = 256; kc = z - 8; }
  int tid = threadIdx.x;
  int hl = tid & 63, tq = tid >> 6;
  int h = ht * 256 + hl * 4;
  int base = kc * CH;
  float a[8][4];
  #pragma unroll
  for (int tt = 0; tt < 8; tt++)
    #pragma unroll
    for (int q = 0; q < 4; q++) a[tt][q] = 0.f;
  const float* wrow = wts + ((long)(b * T_) + tq * 8) * KS + base;
  for (int sl = 0; sl < CH; sl++){
    const u16* wp = Wbuf + ((long)b * KS + base + sl) * H_ + h;
    u32 p0 = *(const u32*)(wp);
    u32 p1 = *(const u32*)(wp + 2);
    float v0 = bf2f((u16)(p0 & 0xffff)), v1 = bf2f((u16)(p0 >> 16));
    float v2 = bf2f((u16)(p1 & 0xffff)), v3 = bf2f((u16)(p1 >> 16));
    #pragma unroll
    for (int tt = 0; tt < 8; tt++){
      float w = wrow[(long)tt * KS + sl];
      a[tt][0] += w * v0; a[tt][1] += w * v1;
      a[tt][2] += w * v2; a[tt][3] += w * v3;
    }
  }
  #pragma unroll
  for (int tt = 0; tt < 8; tt++){
    long o = (long)kc * (2 * M_ * H_) + ((long)(b * T_ + tq * 8 + tt)) * H_ + h;
    *(f32x4*)(pdst + o) = (f32x4){a[tt][0], a[tt][1], a[tt][2], a[tt][3]};
  }
}

__global__ __launch_bounds__(256) void k_red8(const float* __restrict__ pbuf,
                                              float* __restrict__ outp){
  long n = 2L * M_ * H_;
  long i = (long)blockIdx.x * 256 + threadIdx.x;
  if (i >= n) return;
  float s = 0.f;
  #pragma unroll
  for (int kc = 0; kc < 8; kc++) s += pbuf[(long)kc * n + i];
  outp[i] = s;
}

// ---------------- fused gate + pgen ----------------

__global__ __launch_bounds__(256) void k_gatepgen(const float* __restrict__ ctx,
    const float* __restrict__ rctx, const float* __restrict__ gate_w,
    const float* __restrict__ gate_b, float* __restrict__ contexts,
    u16* __restrict__ ch_bf, const float* __restrict__ h_all,
    const u16* __restrict__ x_bf, const float* __restrict__ pgen_w,
    const float* __restrict__ pgen_b, float* __restrict__ pg){
  int rid = blockIdx.x, tid = threadIdx.x;
  int b = rid / T_, t = rid % T_;
  const float* c  = ctx  + (long)rid * H_;
  const float* rc = rctx + (long)rid * H_;
  float part = 0.f;
  for (int h = tid; h < H_; h += 256) part += c[h] * gate_w[h] + rc[h] * gate_w[H_ + h];
  for (int o = 32; o > 0; o >>= 1) part += __shfl_xor(part, o);
  __shared__ float red[4];
  if ((tid & 63) == 0) red[tid >> 6] = part;
  __syncthreads();
  float g = sigmoid_(red[0] + red[1] + red[2] + red[3] + gate_b[0]);
  for (int h = tid; h < H_; h += 256){
    float v = g * c[h] + (1.f - g) * rc[h];
    contexts[(long)rid * H_ + h] = v;
    ch_bf[(long)rid * 1024 + h] = f2bf(v);
  }
  float p0 = 0.f, p1 = 0.f, p2 = 0.f;
  for (int k = tid; k < 1536; k += 256){
    float v;
    if (k < 512)       v = g * c[k] + (1.f - g) * rc[k];
    else if (k < 1024) v = h_all[((2 * T_ + t) * B_ + b) * H_ + (k - 512)];
    else               v = bf2f(x_bf[(long)rid * H_ + (k - 1024)]);
    p0 += v * pgen_w[k * 3 + 0];
    p1 += v * pgen_w[k * 3 + 1];
    p2 += v * pgen_w[k * 3 + 2];
  }
  for (int o = 32; o > 0; o >>= 1){
    p0 += __shfl_xor(p0, o); p1 += __shfl_xor(p1, o); p2 += __shfl_xor(p2, o);
  }
  __shared__ float r0[4], r1[4], r2[4];
  if ((tid & 63) == 0){ r0[tid >> 6] = p0; r1[tid >> 6] = p1; r2[tid >> 6] = p2; }
  __syncthreads();
  if (tid == 0){
    p0 = r0[0]+r0[1]+r0[2]+r0[3] + pgen_b[0];
    p1 = r1[0]+r1[1]+r1[2]+r1[3] + pgen_b[1];
    p2 = r2[0]+r2[1]+r2[2]+r2[3] + pgen_b[2];
    float m = fmaxf(p0, fmaxf(p1, p2));
    float e0 = __expf(p0 - m), e1 = __expf(p1 - m), e2 = __expf(p2 - m);
    float inv = 1.f / (e0 + e1 + e2);
    pg[rid * 3 + 0] = e0 * inv;
    pg[rid * 3 + 1] = e1 * inv;
    pg[rid * 3 + 2] = e2 * inv;
  }
}

// ---------------- final assembly ----------------

__global__ __launch_bounds__(256) void k_final_vocab(float* __restrict__ fin,
    const float* __restrict__ pm, const float* __restrict__ ps,
    const float* __restrict__ pg){
  int rid = blockIdx.y, tid = threadIdx.x;
  const float* mrow = pm + (long)rid * 392;
  const float* srow = ps + (long)rid * 392;
  float m = -1e30f, s = 0.f;
  for (int q = tid; q < 391; q += 256){
    float m2 = mrow[q], s2 = srow[q];
    float M = fmaxf(m, m2);
    s = s * __expf(m - M) + s2 * __expf(m2 - M);
    m = M;
  }
  for (int o = 32; o > 0; o >>= 1){
    float m2 = __shfl_xor(m, o), s2 = __shfl_xor(s, o);
    float M = fmaxf(m, m2);
    s = s * __expf(m - M) + s2 * __expf(m2 - M);
    m = M;
  }
  __shared__ float rm[4], rs[4], fm, fs;
  if ((tid & 63) == 0){ rm[tid >> 6] = m; rs[tid >> 6] = s; }
  __syncthreads();
  if (tid == 0){
    float Mx = rm[0], Sx = rs[0];
    for (int q = 1; q < 4; q++){
      float M2 = fmaxf(Mx, rm[q]);
      Sx = Sx * __expf(Mx - M2) + rs[q] * __expf(rm[q] - M2);
      Mx = M2;
    }
    fm = Mx; fs = Sx;
  }
  __syncthreads();
  float mx = fm;
  float scale = pg[rid * 3 + 0] / fs;
  int v = (blockIdx.x * 256 + tid) * 2;
  if (v >= FINW) return;
  long base = (long)rid * FINW;
  if (v + 1 < V_){
    float2* p = (float2*)(fin + base + v);
    float2 x = *p;
    x.x = __expf(x.x - mx) * scale;
    x.y = __expf(x.y - mx) * scale;
    *p = x;
  } else {
    for (int q = 0; q < 2 && v + q < FINW; q++){
      float x = fin[base + v + q];
      fin[base + v + q] = (v + q < V_) ? __expf(x - mx) * scale : 0.f;
    }
  }
}

__global__ __launch_bounds__(512) void k_scatter(float* __restrict__ fin,
    const float* __restrict__ aw, const float* __restrict__ raBuf,
    const float* __restrict__ pg, const int* __restrict__ src_oov,
    const int* __restrict__ ref_oovs){
  int rid = blockIdx.x, tid = threadIdx.x;
  int b = rid / T_;
  if (tid < 256){
    float p1 = pg[rid * 3 + 1];
    for (int s = tid; s < S_; s += 256){
      float val = p1 * aw[(long)rid * S_ + s];
      int idx = src_oov[b * S_ + s];
      atomicAdd(fin + (long)rid * FINW + idx, val);
    }
  } else {
    int t2 = tid - 256;
    float p2 = pg[rid * 3 + 2];
    for (int i = t2; i < RL_; i += 256){
      float val = p2 * raBuf[(long)rid * RL_ + i];
      int idx = ref_oovs[b * RL_ + i];
      atomicAdd(fin + (long)rid * FINW + idx, val);
    }
  }
}

// ---------------- host ----------------

extern "C" void kernel_launch(void* const* d_in, const int* in_sizes, int n_in,
                              void* d_out, int out_size, void* d_ws, size_t ws_size,
                              hipStream_t stream)
{
  (void)in_sizes; (void)n_in; (void)out_size;
  const int*   tokens   = (const int*)  d_in[0];
  const int*   src_oov  = (const int*)  d_in[1];
  const int*   ref_oovs = (const int*)  d_in[2];
  const float* cwr      = (const float*)d_in[7];
  const float* rwr      = (const float*)d_in[8];
  const float* rdr      = (const float*)d_in[9];
  const float* hidden0  = (const float*)d_in[10];
  const float* embed_w  = (const float*)d_in[11];
  const float* gru_wih  = (const float*)d_in[12];
  const float* gru_whh  = (const float*)d_in[13];
  const float* gru_bih  = (const float*)d_in[14];
  const float* gru_bhh  = (const float*)d_in[15];
  const float* attn_Wd  = (const float*)d_in[16];
  const float* attn_We  = (const float*)d_in[17];
  const float* attn_v   = (const float*)d_in[18];
  const float* hd_Wd    = (const float*)d_in[19];
  const float* hd_We    = (const float*)d_in[20];
  const float* hd_v     = (const float*)d_in[21];
  const float* hw_Wd    = (const float*)d_in[22];
  const float* hw_We    = (const float*)d_in[23];
  const float* hw_v     = (const float*)d_in[24];
  const float* gate_w   = (const float*)d_in[25];
  const float* gate_b   = (const float*)d_in[26];
  const float* fc_w     = (const float*)d_in[27];
  const float* fc_b     = (const float*)d_in[28];
  const float* out_w    = (const float*)d_in[29];
  const float* out_b    = (const float*)d_in[30];
  const float* pgen_w   = (const float*)d_in[31];
  const float* pgen_b   = (const float*)d_in[32];

  float* fin = (float*)d_out;                      // [M_][FINW]
  float* aw  = fin + (long)M_ * FINW;              // [M_][S_] attn_dists output

  char* wptr = (char*)d_ws;
  auto alloc = [&](size_t nbytes) -> void* {
    void* p = (void*)wptr;
    wptr += (nbytes + 255) & ~(size_t)255;
    return p;
  };
  float* gx0      = (float*)alloc((size_t)M_ * 1536 * 4);
  float* h_all    = (float*)alloc((size_t)NL_ * T_ * B_ * H_ * 4);
  float* dec_all  = (float*)alloc((size_t)M_ * 1536 * 4);
  float* raBuf    = (float*)alloc((size_t)M_ * RL_ * 4);
  float* ad       = (float*)alloc((size_t)M_ * R_ * 4);
  float* ctx      = (float*)alloc((size_t)M_ * H_ * 4);   // ctx,rctx contiguous
  float* rctx     = (float*)alloc((size_t)M_ * H_ * 4);
  float* contexts = (float*)alloc((size_t)M_ * H_ * 4);
  float* pg       = (float*)alloc((size_t)M_ * 3 * 4);
  float* pm       = (float*)alloc((size_t)M_ * 392 * 4);
  float* ps       = (float*)alloc((size_t)M_ * 392 * 4);
  float* doc_proj = (float*)alloc((size_t)B_ * R_ * H_ * 4);
  float* pbuf     = (float*)alloc((size_t)8 * 2 * M_ * H_ * 4);
  unsigned int* gru_cnt = (unsigned int*)alloc((GRUB + NCONV) * 16 * 4);
  u16* x_bf       = (u16*)alloc((size_t)M_ * H_ * 2);
  u16* ch_bf      = (u16*)alloc((size_t)M_ * 1024 * 2);
  u16* whh_h16    = (u16*)alloc((size_t)NL_ * 1536 * H_ * 2);
  u16* wih_h16    = (u16*)alloc((size_t)NL_ * 1536 * H_ * 2);
  u16* wih0_bf    = (u16*)alloc((size_t)1536 * H_ * 2);
  u16* WT         = (u16*)alloc((size_t)6 * H_ * H_ * 2);  // [We x3 | Wd x3]
  u16* fcwT       = (u16*)alloc((size_t)H_ * 1024 * 2);
  u16* fcout_bf   = (u16*)alloc((size_t)M_ * H_ * 2);
  u16* cwr_bf     = (u16*)alloc((size_t)B_ * S_ * H_ * 2);
  u16* enc_bf     = (u16*)alloc((size_t)B_ * S_ * H_ * 2);
  u16* rwr_bf     = (u16*)alloc((size_t)B_ * RL_ * H_ * 2);
  u16* wp_bf      = (u16*)alloc((size_t)B_ * RL_ * H_ * 2);
  u16* rdr_bf     = (u16*)alloc((size_t)B_ * R_ * H_ * 2);
  u16* outwT_ded  = (u16*)alloc((size_t)V_ * H_ * 2);      // 51.2MB, only if ws permits
  bool big = ((char*)outwT_ded + (size_t)V_ * H_ * 2) <= ((char*)d_ws + ws_size);
  u16* outwT = big ? outwT_ded : rwr_bf;   // fallback: alias (dead after awgemm)
  int nshadow = big ? NCONV : 0;

  hipMemsetAsync(gru_cnt, 0, (GRUB + NCONV) * 16 * 4, stream);

  // --- host conversions ---
  k_embed<<<M_, 256, 0, stream>>>(tokens, embed_w, x_bf);
  {
    CJ j0{cwr, cwr_bf, (long)B_ * S_ * H_, 0};
    CJ j1{rwr, rwr_bf, (long)B_ * RL_ * H_, 0};
    CJ j2{gru_whh, whh_h16, (long)NL_ * 1536 * H_, 1};
    CJ j3{gru_wih, wih_h16, (long)NL_ * 1536 * H_, 1};
    CJ j4{rdr, rdr_bf, (long)B_ * R_ * H_, 0};
    CJ j5{gru_wih, wih0_bf, (long)1536 * H_, 0};
    k_conv6<<<dim3(512, 6), 256, 0, stream>>>(j0, j1, j2, j3, j4, j5);
  }
  k_convT6<<<dim3(16, 16, 6), 256, 0, stream>>>(attn_We, hd_We, hw_We,
                                                attn_Wd, hd_Wd, hw_Wd, WT);
  k_convT<<<dim3(16, 32), 256, 0, stream>>>(fc_w, 1024, H_, fcwT);

  // --- gx0 = x @ wih0^T + bih0 ---
  k_gemm_nt<<<dim3(4, 12), 256, 0, stream>>>(x_bf, H_, wih0_bf, H_, gru_bih,
                                             (void*)gx0, 1536, 1536, H_, 0, 1.f);
  if (!big){
    k_gemm_nt<<<dim3(64, 4), 256, 0, stream>>>(cwr_bf, H_, WT, H_, (const float*)0,
                                               (void*)enc_bf, H_, H_, H_, 1, S2C);
    k_gemm_nt<<<dim3(256, 4), 256, 0, stream>>>(rwr_bf, H_, WT + 2 * H_ * H_, H_, (const float*)0,
                                                (void*)wp_bf, H_, H_, H_, 1, S2C);
    k_gemm_nt<<<dim3(1, 4), 256, 0, stream>>>(rdr_bf, H_, WT + H_ * H_, H_, (const float*)0,
                                              (void*)doc_proj, H_, H_, H_, 0, S2C);
  }

  // --- mega kernel ---
  k_gru_mega<<<GRUB + nshadow, 512, 0, stream>>>(gx0, wih_h16, whh_h16, gru_bih, gru_bhh,
                                                 hidden0, h_all, ch_bf, gru_cnt,
                                                 out_w, outwT, cwr_bf, rwr_bf, rdr_bf,
                                                 WT, enc_bf, wp_bf, doc_proj, big ? 1 : 0);

  // dec projections (stacked, scaled)
  k_gemm_nt<<<dim3(4, 12), 256, 0, stream>>>(ch_bf + 512, 1024, WT + 3 * H_ * H_, H_,
                                             (const float*)0, (void*)dec_all, 1536, 1536, H_, 0, S2C);

  // --- attention ---
  k_scores2<<<dim3(16, 40, 4), 256, 0, stream>>>(enc_bf, wp_bf, dec_all, attn_v, hw_v, aw, raBuf);
  k_smax_scd<<<dim3(M_, 2), 256, 0, stream>>>(aw, doc_proj, dec_all, hd_v, ad);
  k_aww_ra<<<dim3(M_, R_), 256, 0, stream>>>(raBuf, ad);

  // --- ctx / rctx via split-K streaming ---
  k_awgemm2<<<dim3(B_, 2, 16), 256, 0, stream>>>(aw, raBuf, cwr_bf, rwr_bf, pbuf);
  if (!big)
    k_convT<<<dim3(1563, 16), 256, 0, stream>>>(out_w, H_, V_, outwT);
  k_red8<<<(2 * M_ * H_ + 255) / 256, 256, 0, stream>>>(pbuf, ctx);

  k_gatepgen<<<M_, 256, 0, stream>>>(ctx, rctx, gate_w, gate_b, contexts, ch_bf,
                                     h_all, x_bf, pgen_w, pgen_b, pg);

  // --- output head ---
  k_gemm_nt<<<dim3(4, 4), 256, 0, stream>>>(ch_bf, 1024, fcwT, 1024, fc_b,
                                            (void*)fcout_bf, H_, H_, 1024, 1, 1.f);
  k_gemm_out<<<dim3(4, 391), 256, 0, stream>>>(fcout_bf, outwT, out_b, fin, pm, ps);
  k_final_vocab<<<dim3(98, M_), 256, 0, stream>>>(fin, pm, ps, pg);
  k_scatter<<<M_, 512, 0, stream>>>(fin, aw, raBuf, pg, src_oov, ref_oovs);
}